// Round 2
// baseline (219.983 us; speedup 1.0000x reference)
//
#include <hip/hip_runtime.h>

// Attention_72902774882333 — R11 (resubmit; prior rounds failed on infra, not
// kernel): attn software pipeline. Depth-1 register prefetch of next K/V tile
// + double-buffered LDS + ONE barrier per 64-key tile (was 2 + exposed
// global->LDS round trip). setprio(1) around MFMA clusters (T5). K-fragments
// hoisted out of the s-loop. xt/qkv/projout = R10 (proven).
// B=4, C=256, N=4096, H=4, DK=64.

#define BDIM 4
#define CDIM 256
#define NDIM 4096
#define HDIM 4
#define DKDIM 64
#define NQ   (BDIM * HDIM * NDIM)       // 65536
#define NSPLIT 2
#define KPERZ (NDIM / NSPLIT)           // 2048 keys per split
#define QSCALE 0.18033688011112042f     // log2(e)/8

typedef __bf16 bf16x8 __attribute__((ext_vector_type(8)));
typedef float f32x4 __attribute__((ext_vector_type(4)));
typedef short s16x4 __attribute__((ext_vector_type(4)));
typedef unsigned short u16;
typedef unsigned int u32;

__device__ __forceinline__ u16 f2bf(float f) {
  union { __bf16 h; u16 s; } u; u.h = (__bf16)f; return u.s;
}
__device__ __forceinline__ float bf2f(u16 v) {
  union { u32 u; float f; } x; x.u = (u32)v << 16; return x.f;
}
__device__ __forceinline__ u32 pk2(float a, float b) {
  return (u32)f2bf(a) | ((u32)f2bf(b) << 16);
}

// ---------------- x transpose: fp32 [b][c][n] -> bf16 [b][n][256] ----------------
__global__ __launch_bounds__(256) void xt_kernel(
    const float* __restrict__ x, u16* __restrict__ xT)
{
  const int b = blockIdx.z, c0 = blockIdx.y * 64, n0 = blockIdx.x * 64;
  __shared__ __align__(16) float T[64][68];
  const int t = threadIdx.x;
  {
    const int cr = t >> 4, nc = (t & 15) * 4;
    #pragma unroll
    for (int ci = 0; ci < 4; ++ci) {
      const float4 v = *(const float4*)&x[((size_t)(b * CDIM + c0 + cr + ci * 16)) * NDIM + n0 + nc];
      *(float4*)&T[cr + ci * 16][nc] = v;
    }
  }
  __syncthreads();
  {
    const int n = t >> 2, g = t & 3;
    union { u16 u[16]; uint4 v[2]; } pk;
    #pragma unroll
    for (int u_ = 0; u_ < 16; ++u_) pk.u[u_] = f2bf(T[g * 16 + u_][n]);
    uint4* dst = (uint4*)&xT[((size_t)(b * NDIM + n0 + n)) * CDIM + c0 + g * 16];
    dst[0] = pk.v[0]; dst[1] = pk.v[1];
  }
}

// ---------------- fused Q/K/V projection (o-tile 128) ----------------
// Grid (NDIM/64, 6, BDIM): p = y>>1, o0 = (y&1)*128.
// Q/K -> bf16 [b][n][256] head-major (Q scaled log2e/8 incl bias);
// V -> bf16 [b][c][n]. Weights read fp32, converted inline.
__global__ __launch_bounds__(256, 4) void qkv_kernel(
    const u16* __restrict__ xT,
    const float* __restrict__ wq, const float* __restrict__ bq,
    const float* __restrict__ wk, const float* __restrict__ bk,
    const float* __restrict__ wv, const float* __restrict__ bv,
    u16* __restrict__ qT, u16* __restrict__ kT, u16* __restrict__ vB)
{
  const int b = blockIdx.z;
  const int p = blockIdx.y >> 1;
  const int o0 = (blockIdx.y & 1) * 128;
  const int n0 = blockIdx.x * 64;
  const float* wsel = (p == 0) ? wq : (p == 1) ? wk : wv;
  const float* bsel = (p == 0) ? bq : (p == 1) ? bk : bv;
  const float wscale = (p == 0) ? QSCALE : 1.0f;

  __shared__ __align__(16) u16 XTs[64][40];
  __shared__ __align__(16) u16 Ws[128][40];
  const int t = threadIdx.x, lane = t & 63, w = t >> 6;
  const int qd = lane >> 4, lm = lane & 15;
  const int sr = t >> 2, sg = (t & 3) * 8;
  const int r2 = t >> 1, g2 = (t & 1) * 16;

  const u16* xsrc = xT + ((size_t)(b * NDIM + n0 + sr)) * CDIM + sg;
  const float* wsrc = wsel + (size_t)(o0 + r2) * CDIM + g2;

  f32x4 acc[4][2];
  #pragma unroll
  for (int nt = 0; nt < 4; ++nt)
    #pragma unroll
    for (int j = 0; j < 2; ++j) acc[nt][j] = (f32x4){0.f, 0.f, 0.f, 0.f};

  for (int cs = 0; cs < 8; ++cs) {
    __syncthreads();
    *(uint4*)&XTs[sr][sg] = *(const uint4*)(xsrc + cs * 32);
    {
      const float4 w0 = *(const float4*)(wsrc + cs * 32);
      const float4 w1 = *(const float4*)(wsrc + cs * 32 + 4);
      const float4 w2 = *(const float4*)(wsrc + cs * 32 + 8);
      const float4 w3 = *(const float4*)(wsrc + cs * 32 + 12);
      union { u32 p[8]; uint4 v[2]; } pw;
      pw.p[0] = pk2(w0.x * wscale, w0.y * wscale);
      pw.p[1] = pk2(w0.z * wscale, w0.w * wscale);
      pw.p[2] = pk2(w1.x * wscale, w1.y * wscale);
      pw.p[3] = pk2(w1.z * wscale, w1.w * wscale);
      pw.p[4] = pk2(w2.x * wscale, w2.y * wscale);
      pw.p[5] = pk2(w2.z * wscale, w2.w * wscale);
      pw.p[6] = pk2(w3.x * wscale, w3.y * wscale);
      pw.p[7] = pk2(w3.z * wscale, w3.w * wscale);
      *(uint4*)&Ws[r2][g2]     = pw.v[0];
      *(uint4*)&Ws[r2][g2 + 8] = pw.v[1];
    }
    __syncthreads();
    bf16x8 xf[4], wf[2];
    #pragma unroll
    for (int nt = 0; nt < 4; ++nt) xf[nt] = *(const bf16x8*)&XTs[16 * nt + lm][qd * 8];
    #pragma unroll
    for (int j = 0; j < 2; ++j) wf[j] = *(const bf16x8*)&Ws[32 * w + 16 * j + lm][qd * 8];
    #pragma unroll
    for (int nt = 0; nt < 4; ++nt)
      #pragma unroll
      for (int j = 0; j < 2; ++j) {
        if (p < 2)
          acc[nt][j] = __builtin_amdgcn_mfma_f32_16x16x32_bf16(xf[nt], wf[j], acc[nt][j], 0, 0, 0);
        else
          acc[nt][j] = __builtin_amdgcn_mfma_f32_16x16x32_bf16(wf[j], xf[nt], acc[nt][j], 0, 0, 0);
      }
  }

  if (p < 2) {
    // D[m=n][col=o]: n = n0+16nt+4qd+r, o = o0+32w+16j+lm
    u16* out = (p == 0) ? qT : kT;
    #pragma unroll
    for (int j = 0; j < 2; ++j) {
      const int og = o0 + 32 * w + 16 * j + lm;
      const float bv2 = bsel[og] * wscale;
      #pragma unroll
      for (int nt = 0; nt < 4; ++nt)
        #pragma unroll
        for (int r = 0; r < 4; ++r) {
          const int n = n0 + 16 * nt + 4 * qd + r;
          out[((size_t)(b * NDIM + n)) * CDIM + og] = f2bf(acc[nt][j][r] + bv2);
        }
    }
  } else {
    // D[m=o][col=n]: o = o0+32w+16j+4qd+r, n = n0+16nt+lm
    #pragma unroll
    for (int j = 0; j < 2; ++j) {
      const float4 b4 = *(const float4*)&bsel[o0 + 32 * w + 16 * j + 4 * qd];
      const float bvr[4] = {b4.x, b4.y, b4.z, b4.w};
      #pragma unroll
      for (int nt = 0; nt < 4; ++nt)
        #pragma unroll
        for (int r = 0; r < 4; ++r) {
          const int og = o0 + 32 * w + 16 * j + 4 * qd + r;
          const int n = n0 + 16 * nt + lm;
          vB[((size_t)(b * CDIM + og)) * NDIM + n] = f2bf(acc[nt][j][r] + bvr[r]);
        }
    }
  }
}

// ---------------- K-split(2) S^T-form MFMA flash attention ----------------
// R11: depth-1 pipelined. Per 64-key tile: issue next tile's global loads ->
// compute current LDS buffer -> ds_write other buffer -> ONE barrier.
__global__ __launch_bounds__(256, 4) void attn_kernel(
    const u16* __restrict__ qT, const u16* __restrict__ kT,
    const u16* __restrict__ vB, u16* __restrict__ Opart,
    float* __restrict__ Lp)
{
  const int bh = blockIdx.y, b = bh >> 2, h = bh & 3;
  const int n0 = blockIdx.x * 128;
  const int z  = blockIdx.z;

  // [buf][0]=K tile, [buf][1]=V tile. 2*2*64*72*2B = 36 KB -> still 4 blocks/CU.
  __shared__ __align__(16) u16 KV[2][2][64][72];

  const int t = threadIdx.x, lane = t & 63, w = t >> 6;
  const int qd = lane >> 4, lm = lane & 15;

  // Q fragments straight from global: rows are wave-private, read once.
  bf16x8 qf[2][2];
  {
    const u16* qbase = qT + ((size_t)(b * NDIM) + n0) * CDIM + h * 64;
    #pragma unroll
    for (int s = 0; s < 2; ++s)
      #pragma unroll
      for (int hh = 0; hh < 2; ++hh)
        qf[s][hh] = *(const bf16x8*)(qbase +
            (size_t)(16 * (2 * w + s) + lm) * CDIM + 32 * hh + qd * 8);
  }

  float l_i[2] = {0.f, 0.f};
  f32x4 oa[2][4];
  #pragma unroll
  for (int s = 0; s < 2; ++s)
    #pragma unroll
    for (int dt = 0; dt < 4; ++dt) oa[s][dt] = (f32x4){0.f, 0.f, 0.f, 0.f};

  const int sr = t >> 2, sg = (t & 3) * 16;
  const u16* kptr = kT + ((size_t)(b * NDIM) + z * KPERZ + sr) * CDIM + h * 64 + sg;
  const u16* vptr = vB + ((size_t)(b * CDIM) + h * 64 + sr) * NDIM + z * KPERZ + sg;

  // prologue: stage tile 0 into buffer 0
  {
    const uint4 ka = *(const uint4*)(kptr);
    const uint4 kb = *(const uint4*)(kptr + 8);
    const uint4 va = *(const uint4*)(vptr);
    const uint4 vv = *(const uint4*)(vptr + 8);
    kptr += (size_t)64 * CDIM;
    vptr += 64;
    uint4* kd = (uint4*)&KV[0][0][sr][sg]; kd[0] = ka; kd[1] = kb;
    uint4* vd = (uint4*)&KV[0][1][sr][sg]; vd[0] = va; vd[1] = vv;
  }
  __syncthreads();

  uint4 ka, kb, va, vv;
  int cur = 0;
  #pragma unroll 1
  for (int it = 0; it < KPERZ / 64; ++it) {
    const bool pf = (it + 1 < KPERZ / 64);
    if (pf) {
      // issue next tile's loads now; latency hides under this tile's compute
      ka = *(const uint4*)(kptr);
      kb = *(const uint4*)(kptr + 8);
      va = *(const uint4*)(vptr);
      vv = *(const uint4*)(vptr + 8);
      kptr += (size_t)64 * CDIM;
      vptr += 64;
    }
    __builtin_amdgcn_sched_barrier(0);   // pin load issue before compute

    const u16 (*Kt)[72] = KV[cur][0];
    const u16 (*Vt)[72] = KV[cur][1];

    // P fragments, packed bf16 at production: pk[s][c].v is the PV B-operand
    union { u16 u[4]; s16x4 v; } pk[2][4];
    float rs[2] = {0.f, 0.f};

    #pragma unroll
    for (int nt = 0; nt < 4; ++nt) {
      const bf16x8 kf0 = *(const bf16x8*)&Kt[16 * nt + lm][qd * 8];
      const bf16x8 kf1 = *(const bf16x8*)&Kt[16 * nt + lm][32 + qd * 8];
      #pragma unroll
      for (int s = 0; s < 2; ++s) {
        f32x4 zz = (f32x4){0.f, 0.f, 0.f, 0.f};
        __builtin_amdgcn_s_setprio(1);
        zz = __builtin_amdgcn_mfma_f32_16x16x32_bf16(kf0, qf[s][0], zz, 0, 0, 0);
        zz = __builtin_amdgcn_mfma_f32_16x16x32_bf16(kf1, qf[s][1], zz, 0, 0, 0);
        __builtin_amdgcn_s_setprio(0);
        #pragma unroll
        for (int r = 0; r < 4; ++r) {
          const float p = __builtin_amdgcn_exp2f(zz[r]);
          pk[s][nt].u[r] = f2bf(p);
          rs[s] += p;
        }
      }
    }
    l_i[0] += rs[0];
    l_i[1] += rs[1];

    #pragma unroll
    for (int c = 0; c < 4; ++c) {
      s16x4 av[4];
      #pragma unroll
      for (int dt = 0; dt < 4; ++dt)
        av[dt] = *(const s16x4*)&Vt[16 * dt + lm][16 * c + 4 * qd];
      __builtin_amdgcn_s_setprio(1);
      #pragma unroll
      for (int dt = 0; dt < 4; ++dt) {
        oa[0][dt] = __builtin_amdgcn_mfma_f32_16x16x16bf16_1k(av[dt], pk[0][c].v, oa[0][dt], 0, 0, 0);
        oa[1][dt] = __builtin_amdgcn_mfma_f32_16x16x16bf16_1k(av[dt], pk[1][c].v, oa[1][dt], 0, 0, 0);
      }
      __builtin_amdgcn_s_setprio(0);
    }

    if (pf) {
      // stage next tile into the other buffer (vmcnt wait is ~free by now)
      uint4* kd = (uint4*)&KV[cur ^ 1][0][sr][sg]; kd[0] = ka; kd[1] = kb;
      uint4* vd = (uint4*)&KV[cur ^ 1][1][sr][sg]; vd[0] = va; vd[1] = vv;
    }
    __syncthreads();   // single barrier per tile
    cur ^= 1;
  }

  // deferred l reduction across the 4 quads (lane bits 4,5)
  #pragma unroll
  for (int s = 0; s < 2; ++s) {
    l_i[s] += __shfl_xor(l_i[s], 16);
    l_i[s] += __shfl_xor(l_i[s], 32);
  }

  // epilogue: normalize, transpose via LDS (overlay first KV buffer), write rows.
  // Loop-final barrier already separates last tile's reads from this overlay.
  u16 (*Ot)[72] = (u16(*)[72])&KV[0][0][0][0];   // [128][72] fits in buffer 0
  #pragma unroll
  for (int s = 0; s < 2; ++s) {
    const float inv = 1.0f / l_i[s];
    #pragma unroll
    for (int dt = 0; dt < 4; ++dt)
      #pragma unroll
      for (int r = 0; r < 4; ++r)
        Ot[16 * (2 * w + s) + lm][16 * dt + 4 * qd + r] = f2bf(oa[s][dt][r] * inv);
  }
  if (qd == 0) {
    const size_t lbase = ((size_t)z * (BDIM * HDIM) + bh) * NDIM;
    #pragma unroll
    for (int s = 0; s < 2; ++s)
      Lp[lbase + n0 + 16 * (2 * w + s) + lm] = l_i[s];
  }
  __syncthreads();
  {
    const int r = t >> 1, g = (t & 1) * 32;
    u16* dst = Opart + (((size_t)z * (BDIM * HDIM) + bh) * NDIM + n0 + r) * DKDIM + g;
    const uint4* srcp = (const uint4*)&Ot[r][g];
    uint4* d4 = (uint4*)dst;
    d4[0] = srcp[0]; d4[1] = srcp[1]; d4[2] = srcp[2]; d4[3] = srcp[3];
  }
}

// ---------------- output projection, o-tile 128, fused 2-way combine ----------------
// Grid (NDIM/64, 2, BDIM). Combine weights = l ratios (shift-free partials).
__global__ __launch_bounds__(256, 4) void projout_kernel(
    const u16* __restrict__ Opart, const float* __restrict__ Lp,
    const float* __restrict__ wp, const float* __restrict__ bp,
    const float* __restrict__ res, float* __restrict__ out)
{
  const int b = blockIdx.z, o0 = blockIdx.y * 128, n0 = blockIdx.x * 64;
  __shared__ __align__(16) u16 XTs[64][40];
  __shared__ __align__(16) u16 Ws[128][40];
  const int t = threadIdx.x, lane = t & 63, w = t >> 6;
  const int qd = lane >> 4, lm = lane & 15;
  const int sr = t >> 2, sg = (t & 3) * 8;
  const int r2 = t >> 1, g2 = (t & 1) * 16;

  float wh[4][NSPLIT];
  #pragma unroll
  for (int hh = 0; hh < 4; ++hh) {
    const size_t i0 = ((size_t)(b * HDIM + hh)) * NDIM + n0 + sr;
    float l[NSPLIT], tot = 0.f;
    #pragma unroll
    for (int zz = 0; zz < NSPLIT; ++zz) { l[zz] = Lp[(size_t)zz * NQ + i0]; tot += l[zz]; }
    const float iv = 1.0f / tot;
    #pragma unroll
    for (int zz = 0; zz < NSPLIT; ++zz) wh[hh][zz] = l[zz] * iv;
  }

  const float* wsrc = wp + (size_t)(o0 + r2) * CDIM + g2;

  f32x4 acc[4][2];
  #pragma unroll
  for (int nt = 0; nt < 4; ++nt)
    #pragma unroll
    for (int j = 0; j < 2; ++j) acc[nt][j] = (f32x4){0.f, 0.f, 0.f, 0.f};

  for (int cs = 0; cs < 8; ++cs) {
    const int c0 = cs * 32;
    const int hh = c0 >> 6;
    const int dk = (c0 & 63) + sg;
    __syncthreads();
    {
      const size_t obase = (((size_t)(b * HDIM + hh)) * NDIM + n0 + sr) * DKDIM + dk;
      float v[8] = {0.f, 0.f, 0.f, 0.f, 0.f, 0.f, 0.f, 0.f};
      #pragma unroll
      for (int zz = 0; zz < NSPLIT; ++zz) {
        union { u16 u[8]; uint4 q; } a;
        a.q = *(const uint4*)(Opart + (size_t)zz * NQ * DKDIM + obase);
        const float wz = wh[hh][zz];
        #pragma unroll
        for (int j = 0; j < 8; ++j) v[j] = fmaf(wz, bf2f(a.u[j]), v[j]);
      }
      union { u16 u[8]; uint4 q; } ov;
      #pragma unroll
      for (int j = 0; j < 8; ++j) ov.u[j] = f2bf(v[j]);
      *(uint4*)&XTs[sr][sg] = ov.q;
      const float4 wv0 = *(const float4*)(wsrc + c0);
      const float4 wv1 = *(const float4*)(wsrc + c0 + 4);
      const float4 wv2 = *(const float4*)(wsrc + c0 + 8);
      const float4 wv3 = *(const float4*)(wsrc + c0 + 12);
      union { u32 p[8]; uint4 v[2]; } pw;
      pw.p[0] = pk2(wv0.x, wv0.y); pw.p[1] = pk2(wv0.z, wv0.w);
      pw.p[2] = pk2(wv1.x, wv1.y); pw.p[3] = pk2(wv1.z, wv1.w);
      pw.p[4] = pk2(wv2.x, wv2.y); pw.p[5] = pk2(wv2.z, wv2.w);
      pw.p[6] = pk2(wv3.x, wv3.y); pw.p[7] = pk2(wv3.z, wv3.w);
      *(uint4*)&Ws[r2][g2]     = pw.v[0];
      *(uint4*)&Ws[r2][g2 + 8] = pw.v[1];
    }
    __syncthreads();
    bf16x8 xf[4], wf[2];
    #pragma unroll
    for (int nt = 0; nt < 4; ++nt) xf[nt] = *(const bf16x8*)&XTs[16 * nt + lm][qd * 8];
    #pragma unroll
    for (int j = 0; j < 2; ++j) wf[j] = *(const bf16x8*)&Ws[32 * w + 16 * j + lm][qd * 8];
    #pragma unroll
    for (int nt = 0; nt < 4; ++nt)
      #pragma unroll
      for (int j = 0; j < 2; ++j)
        acc[nt][j] = __builtin_amdgcn_mfma_f32_16x16x32_bf16(wf[j], xf[nt], acc[nt][j], 0, 0, 0);
  }

  // D[m=o][col=n]: o = o0+32w+16j+4qd+r, n = n0+16nt+lm
  #pragma unroll
  for (int j = 0; j < 2; ++j) {
    const float4 b4 = *(const float4*)&bp[o0 + 32 * w + 16 * j + 4 * qd];
    const float bvr[4] = {b4.x, b4.y, b4.z, b4.w};
    #pragma unroll
    for (int nt = 0; nt < 4; ++nt)
      #pragma unroll
      for (int r = 0; r < 4; ++r) {
        const int og = o0 + 32 * w + 16 * j + 4 * qd + r;
        const int n = n0 + 16 * nt + lm;
        const size_t idx = ((size_t)(b * CDIM + og)) * NDIM + n;
        out[idx] = acc[nt][j][r] + bvr[r] + res[idx];
      }
  }
}

extern "C" void kernel_launch(void* const* d_in, const int* in_sizes, int n_in,
                              void* d_out, int out_size, void* d_ws, size_t ws_size,
                              hipStream_t stream)
{
  const float* x  = (const float*)d_in[0];
  const float* wq = (const float*)d_in[1];
  const float* bq = (const float*)d_in[2];
  const float* wk = (const float*)d_in[3];
  const float* bk = (const float*)d_in[4];
  const float* wv = (const float*)d_in[5];
  const float* bv = (const float*)d_in[6];
  const float* wp = (const float*)d_in[7];
  const float* bp = (const float*)d_in[8];
  float* out = (float*)d_out;

  const size_t sz = (size_t)BDIM * CDIM * NDIM;   // 4.19M elements
  u16* xTb = (u16*)d_ws;
  u16* qTb = xTb + sz;
  u16* kTb = qTb + sz;
  u16* vBb = kTb + sz;
  u16* Opart = vBb + sz;                          // NSPLIT*sz u16
  float* Lp = (float*)(Opart + (size_t)NSPLIT * sz);  // NSPLIT*NQ floats

  const dim3 blk(256);
  xt_kernel<<<dim3(NDIM / 64, CDIM / 64, BDIM), blk, 0, stream>>>(x, xTb);
  qkv_kernel<<<dim3(NDIM / 64, 6, BDIM), blk, 0, stream>>>(
      xTb, wq, bq, wk, bk, wv, bv, qTb, kTb, vBb);
  attn_kernel<<<dim3(NDIM / 128, BDIM * HDIM, NSPLIT), blk, 0, stream>>>(
      qTb, kTb, vBb, Opart, Lp);
  projout_kernel<<<dim3(NDIM / 64, 2, BDIM), blk, 0, stream>>>(
      Opart, Lp, wp, bp, x, out);
}

// Round 3
// 213.156 us; speedup vs baseline: 1.0320x; 1.0320x over previous
//
#include <hip/hip_runtime.h>

// Attention_72902774882333 — R12: occupancy restore. R11's double LDS buffer
// (36KB) capped residency at 4 blocks/CU (Occupancy 36%) and REGRESSED vs R10.
// R12 = single 18KB K/V buffer (8 blocks/CU) + keep the free parts of R11:
// depth-1 register prefetch (VGPR stayed 64), setprio, hoisted K-fragments.
// 2 barriers/tile, global latency hidden by issuing loads a full tile early.
// xt/qkv/projout = R10 (proven). B=4, C=256, N=4096, H=4, DK=64.

#define BDIM 4
#define CDIM 256
#define NDIM 4096
#define HDIM 4
#define DKDIM 64
#define NQ   (BDIM * HDIM * NDIM)       // 65536
#define NSPLIT 2
#define KPERZ (NDIM / NSPLIT)           // 2048 keys per split
#define QSCALE 0.18033688011112042f     // log2(e)/8

typedef __bf16 bf16x8 __attribute__((ext_vector_type(8)));
typedef float f32x4 __attribute__((ext_vector_type(4)));
typedef short s16x4 __attribute__((ext_vector_type(4)));
typedef unsigned short u16;
typedef unsigned int u32;

__device__ __forceinline__ u16 f2bf(float f) {
  union { __bf16 h; u16 s; } u; u.h = (__bf16)f; return u.s;
}
__device__ __forceinline__ float bf2f(u16 v) {
  union { u32 u; float f; } x; x.u = (u32)v << 16; return x.f;
}
__device__ __forceinline__ u32 pk2(float a, float b) {
  return (u32)f2bf(a) | ((u32)f2bf(b) << 16);
}

// ---------------- x transpose: fp32 [b][c][n] -> bf16 [b][n][256] ----------------
__global__ __launch_bounds__(256) void xt_kernel(
    const float* __restrict__ x, u16* __restrict__ xT)
{
  const int b = blockIdx.z, c0 = blockIdx.y * 64, n0 = blockIdx.x * 64;
  __shared__ __align__(16) float T[64][68];
  const int t = threadIdx.x;
  {
    const int cr = t >> 4, nc = (t & 15) * 4;
    #pragma unroll
    for (int ci = 0; ci < 4; ++ci) {
      const float4 v = *(const float4*)&x[((size_t)(b * CDIM + c0 + cr + ci * 16)) * NDIM + n0 + nc];
      *(float4*)&T[cr + ci * 16][nc] = v;
    }
  }
  __syncthreads();
  {
    const int n = t >> 2, g = t & 3;
    union { u16 u[16]; uint4 v[2]; } pk;
    #pragma unroll
    for (int u_ = 0; u_ < 16; ++u_) pk.u[u_] = f2bf(T[g * 16 + u_][n]);
    uint4* dst = (uint4*)&xT[((size_t)(b * NDIM + n0 + n)) * CDIM + c0 + g * 16];
    dst[0] = pk.v[0]; dst[1] = pk.v[1];
  }
}

// ---------------- fused Q/K/V projection (o-tile 128) ----------------
// Grid (NDIM/64, 6, BDIM): p = y>>1, o0 = (y&1)*128.
// Q/K -> bf16 [b][n][256] head-major (Q scaled log2e/8 incl bias);
// V -> bf16 [b][c][n]. Weights read fp32, converted inline.
__global__ __launch_bounds__(256, 4) void qkv_kernel(
    const u16* __restrict__ xT,
    const float* __restrict__ wq, const float* __restrict__ bq,
    const float* __restrict__ wk, const float* __restrict__ bk,
    const float* __restrict__ wv, const float* __restrict__ bv,
    u16* __restrict__ qT, u16* __restrict__ kT, u16* __restrict__ vB)
{
  const int b = blockIdx.z;
  const int p = blockIdx.y >> 1;
  const int o0 = (blockIdx.y & 1) * 128;
  const int n0 = blockIdx.x * 64;
  const float* wsel = (p == 0) ? wq : (p == 1) ? wk : wv;
  const float* bsel = (p == 0) ? bq : (p == 1) ? bk : bv;
  const float wscale = (p == 0) ? QSCALE : 1.0f;

  __shared__ __align__(16) u16 XTs[64][40];
  __shared__ __align__(16) u16 Ws[128][40];
  const int t = threadIdx.x, lane = t & 63, w = t >> 6;
  const int qd = lane >> 4, lm = lane & 15;
  const int sr = t >> 2, sg = (t & 3) * 8;
  const int r2 = t >> 1, g2 = (t & 1) * 16;

  const u16* xsrc = xT + ((size_t)(b * NDIM + n0 + sr)) * CDIM + sg;
  const float* wsrc = wsel + (size_t)(o0 + r2) * CDIM + g2;

  f32x4 acc[4][2];
  #pragma unroll
  for (int nt = 0; nt < 4; ++nt)
    #pragma unroll
    for (int j = 0; j < 2; ++j) acc[nt][j] = (f32x4){0.f, 0.f, 0.f, 0.f};

  for (int cs = 0; cs < 8; ++cs) {
    __syncthreads();
    *(uint4*)&XTs[sr][sg] = *(const uint4*)(xsrc + cs * 32);
    {
      const float4 w0 = *(const float4*)(wsrc + cs * 32);
      const float4 w1 = *(const float4*)(wsrc + cs * 32 + 4);
      const float4 w2 = *(const float4*)(wsrc + cs * 32 + 8);
      const float4 w3 = *(const float4*)(wsrc + cs * 32 + 12);
      union { u32 p[8]; uint4 v[2]; } pw;
      pw.p[0] = pk2(w0.x * wscale, w0.y * wscale);
      pw.p[1] = pk2(w0.z * wscale, w0.w * wscale);
      pw.p[2] = pk2(w1.x * wscale, w1.y * wscale);
      pw.p[3] = pk2(w1.z * wscale, w1.w * wscale);
      pw.p[4] = pk2(w2.x * wscale, w2.y * wscale);
      pw.p[5] = pk2(w2.z * wscale, w2.w * wscale);
      pw.p[6] = pk2(w3.x * wscale, w3.y * wscale);
      pw.p[7] = pk2(w3.z * wscale, w3.w * wscale);
      *(uint4*)&Ws[r2][g2]     = pw.v[0];
      *(uint4*)&Ws[r2][g2 + 8] = pw.v[1];
    }
    __syncthreads();
    bf16x8 xf[4], wf[2];
    #pragma unroll
    for (int nt = 0; nt < 4; ++nt) xf[nt] = *(const bf16x8*)&XTs[16 * nt + lm][qd * 8];
    #pragma unroll
    for (int j = 0; j < 2; ++j) wf[j] = *(const bf16x8*)&Ws[32 * w + 16 * j + lm][qd * 8];
    #pragma unroll
    for (int nt = 0; nt < 4; ++nt)
      #pragma unroll
      for (int j = 0; j < 2; ++j) {
        if (p < 2)
          acc[nt][j] = __builtin_amdgcn_mfma_f32_16x16x32_bf16(xf[nt], wf[j], acc[nt][j], 0, 0, 0);
        else
          acc[nt][j] = __builtin_amdgcn_mfma_f32_16x16x32_bf16(wf[j], xf[nt], acc[nt][j], 0, 0, 0);
      }
  }

  if (p < 2) {
    // D[m=n][col=o]: n = n0+16nt+4qd+r, o = o0+32w+16j+lm
    u16* out = (p == 0) ? qT : kT;
    #pragma unroll
    for (int j = 0; j < 2; ++j) {
      const int og = o0 + 32 * w + 16 * j + lm;
      const float bv2 = bsel[og] * wscale;
      #pragma unroll
      for (int nt = 0; nt < 4; ++nt)
        #pragma unroll
        for (int r = 0; r < 4; ++r) {
          const int n = n0 + 16 * nt + 4 * qd + r;
          out[((size_t)(b * NDIM + n)) * CDIM + og] = f2bf(acc[nt][j][r] + bv2);
        }
    }
  } else {
    // D[m=o][col=n]: o = o0+32w+16j+4qd+r, n = n0+16nt+lm
    #pragma unroll
    for (int j = 0; j < 2; ++j) {
      const float4 b4 = *(const float4*)&bsel[o0 + 32 * w + 16 * j + 4 * qd];
      const float bvr[4] = {b4.x, b4.y, b4.z, b4.w};
      #pragma unroll
      for (int nt = 0; nt < 4; ++nt)
        #pragma unroll
        for (int r = 0; r < 4; ++r) {
          const int og = o0 + 32 * w + 16 * j + 4 * qd + r;
          const int n = n0 + 16 * nt + lm;
          vB[((size_t)(b * CDIM + og)) * NDIM + n] = f2bf(acc[nt][j][r] + bvr[r]);
        }
    }
  }
}

// ---------------- K-split(2) S^T-form MFMA flash attention ----------------
// R12: single 18KB K/V LDS buffer (8 blocks/CU) + depth-1 register prefetch.
// Per 64-key tile: issue next tile's global loads -> barrier -> compute ->
// barrier -> write prefetched regs to LDS.
__global__ __launch_bounds__(256, 4) void attn_kernel(
    const u16* __restrict__ qT, const u16* __restrict__ kT,
    const u16* __restrict__ vB, u16* __restrict__ Opart,
    float* __restrict__ Lp)
{
  const int bh = blockIdx.y, b = bh >> 2, h = bh & 3;
  const int n0 = blockIdx.x * 128;
  const int z  = blockIdx.z;

  // [0]=K tile, [1]=V tile. 2*64*72*2B = 18432 B -> 8 blocks/CU.
  __shared__ __align__(16) u16 KV[2][64][72];

  const int t = threadIdx.x, lane = t & 63, w = t >> 6;
  const int qd = lane >> 4, lm = lane & 15;

  // Q fragments straight from global: rows are wave-private, read once.
  bf16x8 qf[2][2];
  {
    const u16* qbase = qT + ((size_t)(b * NDIM) + n0) * CDIM + h * 64;
    #pragma unroll
    for (int s = 0; s < 2; ++s)
      #pragma unroll
      for (int hh = 0; hh < 2; ++hh)
        qf[s][hh] = *(const bf16x8*)(qbase +
            (size_t)(16 * (2 * w + s) + lm) * CDIM + 32 * hh + qd * 8);
  }

  float l_i[2] = {0.f, 0.f};
  f32x4 oa[2][4];
  #pragma unroll
  for (int s = 0; s < 2; ++s)
    #pragma unroll
    for (int dt = 0; dt < 4; ++dt) oa[s][dt] = (f32x4){0.f, 0.f, 0.f, 0.f};

  const int sr = t >> 2, sg = (t & 3) * 16;
  const u16* kptr = kT + ((size_t)(b * NDIM) + z * KPERZ + sr) * CDIM + h * 64 + sg;
  const u16* vptr = vB + ((size_t)(b * CDIM) + h * 64 + sr) * NDIM + z * KPERZ + sg;

  // prologue: stage tile 0
  {
    const uint4 ka0 = *(const uint4*)(kptr);
    const uint4 kb0 = *(const uint4*)(kptr + 8);
    const uint4 va0 = *(const uint4*)(vptr);
    const uint4 vv0 = *(const uint4*)(vptr + 8);
    kptr += (size_t)64 * CDIM;
    vptr += 64;
    uint4* kd = (uint4*)&KV[0][sr][sg]; kd[0] = ka0; kd[1] = kb0;
    uint4* vd = (uint4*)&KV[1][sr][sg]; vd[0] = va0; vd[1] = vv0;
  }

  uint4 ka, kb, va, vv;
  #pragma unroll 1
  for (int it = 0; it < KPERZ / 64; ++it) {
    const bool pf = (it + 1 < KPERZ / 64);
    if (pf) {
      // issue next tile's loads now; latency hides under this tile's compute
      ka = *(const uint4*)(kptr);
      kb = *(const uint4*)(kptr + 8);
      va = *(const uint4*)(vptr);
      vv = *(const uint4*)(vptr + 8);
      kptr += (size_t)64 * CDIM;
      vptr += 64;
    }
    __builtin_amdgcn_sched_barrier(0);   // pin load issue before compute
    __syncthreads();                     // tile it's LDS writes visible

    // P fragments, packed bf16 at production: pk[s][c].v is the PV B-operand
    union { u16 u[4]; s16x4 v; } pk[2][4];
    float rs[2] = {0.f, 0.f};

    #pragma unroll
    for (int nt = 0; nt < 4; ++nt) {
      const bf16x8 kf0 = *(const bf16x8*)&KV[0][16 * nt + lm][qd * 8];
      const bf16x8 kf1 = *(const bf16x8*)&KV[0][16 * nt + lm][32 + qd * 8];
      #pragma unroll
      for (int s = 0; s < 2; ++s) {
        f32x4 zz = (f32x4){0.f, 0.f, 0.f, 0.f};
        __builtin_amdgcn_s_setprio(1);
        zz = __builtin_amdgcn_mfma_f32_16x16x32_bf16(kf0, qf[s][0], zz, 0, 0, 0);
        zz = __builtin_amdgcn_mfma_f32_16x16x32_bf16(kf1, qf[s][1], zz, 0, 0, 0);
        __builtin_amdgcn_s_setprio(0);
        #pragma unroll
        for (int r = 0; r < 4; ++r) {
          const float p = __builtin_amdgcn_exp2f(zz[r]);
          pk[s][nt].u[r] = f2bf(p);
          rs[s] += p;
        }
      }
    }
    l_i[0] += rs[0];
    l_i[1] += rs[1];

    #pragma unroll
    for (int c = 0; c < 4; ++c) {
      s16x4 av[4];
      #pragma unroll
      for (int dt = 0; dt < 4; ++dt)
        av[dt] = *(const s16x4*)&KV[1][16 * dt + lm][16 * c + 4 * qd];
      __builtin_amdgcn_s_setprio(1);
      #pragma unroll
      for (int dt = 0; dt < 4; ++dt) {
        oa[0][dt] = __builtin_amdgcn_mfma_f32_16x16x16bf16_1k(av[dt], pk[0][c].v, oa[0][dt], 0, 0, 0);
        oa[1][dt] = __builtin_amdgcn_mfma_f32_16x16x16bf16_1k(av[dt], pk[1][c].v, oa[1][dt], 0, 0, 0);
      }
      __builtin_amdgcn_s_setprio(0);
    }

    __syncthreads();                     // all reads of tile it done
    if (pf) {
      // stage next tile (vmcnt wait is ~free: loads issued a full tile ago)
      uint4* kd = (uint4*)&KV[0][sr][sg]; kd[0] = ka; kd[1] = kb;
      uint4* vd = (uint4*)&KV[1][sr][sg]; vd[0] = va; vd[1] = vv;
    }
  }

  // deferred l reduction across the 4 quads (lane bits 4,5)
  #pragma unroll
  for (int s = 0; s < 2; ++s) {
    l_i[s] += __shfl_xor(l_i[s], 16);
    l_i[s] += __shfl_xor(l_i[s], 32);
  }

  // epilogue: normalize, transpose via LDS (overlay K/V region), write rows.
  // Loop's final barrier already separates last tile's reads from this overlay.
  u16 (*Ot)[72] = (u16(*)[72])&KV[0][0][0];   // [128][72] == 2*64*72 exactly
  #pragma unroll
  for (int s = 0; s < 2; ++s) {
    const float inv = 1.0f / l_i[s];
    #pragma unroll
    for (int dt = 0; dt < 4; ++dt)
      #pragma unroll
      for (int r = 0; r < 4; ++r)
        Ot[16 * (2 * w + s) + lm][16 * dt + 4 * qd + r] = f2bf(oa[s][dt][r] * inv);
  }
  if (qd == 0) {
    const size_t lbase = ((size_t)z * (BDIM * HDIM) + bh) * NDIM;
    #pragma unroll
    for (int s = 0; s < 2; ++s)
      Lp[lbase + n0 + 16 * (2 * w + s) + lm] = l_i[s];
  }
  __syncthreads();
  {
    const int r = t >> 1, g = (t & 1) * 32;
    u16* dst = Opart + (((size_t)z * (BDIM * HDIM) + bh) * NDIM + n0 + r) * DKDIM + g;
    const uint4* srcp = (const uint4*)&Ot[r][g];
    uint4* d4 = (uint4*)dst;
    d4[0] = srcp[0]; d4[1] = srcp[1]; d4[2] = srcp[2]; d4[3] = srcp[3];
  }
}

// ---------------- output projection, o-tile 128, fused 2-way combine ----------------
// Grid (NDIM/64, 2, BDIM). Combine weights = l ratios (shift-free partials).
__global__ __launch_bounds__(256, 4) void projout_kernel(
    const u16* __restrict__ Opart, const float* __restrict__ Lp,
    const float* __restrict__ wp, const float* __restrict__ bp,
    const float* __restrict__ res, float* __restrict__ out)
{
  const int b = blockIdx.z, o0 = blockIdx.y * 128, n0 = blockIdx.x * 64;
  __shared__ __align__(16) u16 XTs[64][40];
  __shared__ __align__(16) u16 Ws[128][40];
  const int t = threadIdx.x, lane = t & 63, w = t >> 6;
  const int qd = lane >> 4, lm = lane & 15;
  const int sr = t >> 2, sg = (t & 3) * 8;
  const int r2 = t >> 1, g2 = (t & 1) * 16;

  float wh[4][NSPLIT];
  #pragma unroll
  for (int hh = 0; hh < 4; ++hh) {
    const size_t i0 = ((size_t)(b * HDIM + hh)) * NDIM + n0 + sr;
    float l[NSPLIT], tot = 0.f;
    #pragma unroll
    for (int zz = 0; zz < NSPLIT; ++zz) { l[zz] = Lp[(size_t)zz * NQ + i0]; tot += l[zz]; }
    const float iv = 1.0f / tot;
    #pragma unroll
    for (int zz = 0; zz < NSPLIT; ++zz) wh[hh][zz] = l[zz] * iv;
  }

  const float* wsrc = wp + (size_t)(o0 + r2) * CDIM + g2;

  f32x4 acc[4][2];
  #pragma unroll
  for (int nt = 0; nt < 4; ++nt)
    #pragma unroll
    for (int j = 0; j < 2; ++j) acc[nt][j] = (f32x4){0.f, 0.f, 0.f, 0.f};

  for (int cs = 0; cs < 8; ++cs) {
    const int c0 = cs * 32;
    const int hh = c0 >> 6;
    const int dk = (c0 & 63) + sg;
    __syncthreads();
    {
      const size_t obase = (((size_t)(b * HDIM + hh)) * NDIM + n0 + sr) * DKDIM + dk;
      float v[8] = {0.f, 0.f, 0.f, 0.f, 0.f, 0.f, 0.f, 0.f};
      #pragma unroll
      for (int zz = 0; zz < NSPLIT; ++zz) {
        union { u16 u[8]; uint4 q; } a;
        a.q = *(const uint4*)(Opart + (size_t)zz * NQ * DKDIM + obase);
        const float wz = wh[hh][zz];
        #pragma unroll
        for (int j = 0; j < 8; ++j) v[j] = fmaf(wz, bf2f(a.u[j]), v[j]);
      }
      union { u16 u[8]; uint4 q; } ov;
      #pragma unroll
      for (int j = 0; j < 8; ++j) ov.u[j] = f2bf(v[j]);
      *(uint4*)&XTs[sr][sg] = ov.q;
      const float4 wv0 = *(const float4*)(wsrc + c0);
      const float4 wv1 = *(const float4*)(wsrc + c0 + 4);
      const float4 wv2 = *(const float4*)(wsrc + c0 + 8);
      const float4 wv3 = *(const float4*)(wsrc + c0 + 12);
      union { u32 p[8]; uint4 v[2]; } pw;
      pw.p[0] = pk2(wv0.x, wv0.y); pw.p[1] = pk2(wv0.z, wv0.w);
      pw.p[2] = pk2(wv1.x, wv1.y); pw.p[3] = pk2(wv1.z, wv1.w);
      pw.p[4] = pk2(wv2.x, wv2.y); pw.p[5] = pk2(wv2.z, wv2.w);
      pw.p[6] = pk2(wv3.x, wv3.y); pw.p[7] = pk2(wv3.z, wv3.w);
      *(uint4*)&Ws[r2][g2]     = pw.v[0];
      *(uint4*)&Ws[r2][g2 + 8] = pw.v[1];
    }
    __syncthreads();
    bf16x8 xf[4], wf[2];
    #pragma unroll
    for (int nt = 0; nt < 4; ++nt) xf[nt] = *(const bf16x8*)&XTs[16 * nt + lm][qd * 8];
    #pragma unroll
    for (int j = 0; j < 2; ++j) wf[j] = *(const bf16x8*)&Ws[32 * w + 16 * j + lm][qd * 8];
    #pragma unroll
    for (int nt = 0; nt < 4; ++nt)
      #pragma unroll
      for (int j = 0; j < 2; ++j)
        acc[nt][j] = __builtin_amdgcn_mfma_f32_16x16x32_bf16(wf[j], xf[nt], acc[nt][j], 0, 0, 0);
  }

  // D[m=o][col=n]: o = o0+32w+16j+4qd+r, n = n0+16nt+lm
  #pragma unroll
  for (int j = 0; j < 2; ++j) {
    const float4 b4 = *(const float4*)&bp[o0 + 32 * w + 16 * j + 4 * qd];
    const float bvr[4] = {b4.x, b4.y, b4.z, b4.w};
    #pragma unroll
    for (int nt = 0; nt < 4; ++nt)
      #pragma unroll
      for (int r = 0; r < 4; ++r) {
        const int og = o0 + 32 * w + 16 * j + 4 * qd + r;
        const int n = n0 + 16 * nt + lm;
        const size_t idx = ((size_t)(b * CDIM + og)) * NDIM + n;
        out[idx] = acc[nt][j][r] + bvr[r] + res[idx];
      }
  }
}

extern "C" void kernel_launch(void* const* d_in, const int* in_sizes, int n_in,
                              void* d_out, int out_size, void* d_ws, size_t ws_size,
                              hipStream_t stream)
{
  const float* x  = (const float*)d_in[0];
  const float* wq = (const float*)d_in[1];
  const float* bq = (const float*)d_in[2];
  const float* wk = (const float*)d_in[3];
  const float* bk = (const float*)d_in[4];
  const float* wv = (const float*)d_in[5];
  const float* bv = (const float*)d_in[6];
  const float* wp = (const float*)d_in[7];
  const float* bp = (const float*)d_in[8];
  float* out = (float*)d_out;

  const size_t sz = (size_t)BDIM * CDIM * NDIM;   // 4.19M elements
  u16* xTb = (u16*)d_ws;
  u16* qTb = xTb + sz;
  u16* kTb = qTb + sz;
  u16* vBb = kTb + sz;
  u16* Opart = vBb + sz;                          // NSPLIT*sz u16
  float* Lp = (float*)(Opart + (size_t)NSPLIT * sz);  // NSPLIT*NQ floats

  const dim3 blk(256);
  xt_kernel<<<dim3(NDIM / 64, CDIM / 64, BDIM), blk, 0, stream>>>(x, xTb);
  qkv_kernel<<<dim3(NDIM / 64, 6, BDIM), blk, 0, stream>>>(
      xTb, wq, bq, wk, bk, wv, bv, qTb, kTb, vBb);
  attn_kernel<<<dim3(NDIM / 128, BDIM * HDIM, NSPLIT), blk, 0, stream>>>(
      qTb, kTb, vBb, Opart, Lp);
  projout_kernel<<<dim3(NDIM / 64, 2, BDIM), blk, 0, stream>>>(
      Opart, Lp, wp, bp, x, out);
}

// Round 4
// 212.454 us; speedup vs baseline: 1.0354x; 1.0033x over previous
//
#include <hip/hip_runtime.h>

// Attention_72902774882333 — R13: NSPLIT 2->4. R12 counters showed attn is
// GRID-limited: 1024 blocks = 4 blocks/CU = 50% occupancy cap (measured 36.6%),
// while VGPR=64 and LDS=18KB both allow 8 blocks/CU. The old "split-4 buys no
// occupancy" note predates the VGPR=64 body and is stale. NSPLIT=4 -> 2048
// blocks = 8 blocks/CU. Attn body = R12 (single 18KB buffer, depth-1 reg
// prefetch, setprio, hoisted K-frags). projout combines 4 partials.
// B=4, C=256, N=4096, H=4, DK=64.

#define BDIM 4
#define CDIM 256
#define NDIM 4096
#define HDIM 4
#define DKDIM 64
#define NQ   (BDIM * HDIM * NDIM)       // 65536
#define NSPLIT 4
#define KPERZ (NDIM / NSPLIT)           // 1024 keys per split
#define QSCALE 0.18033688011112042f     // log2(e)/8

typedef __bf16 bf16x8 __attribute__((ext_vector_type(8)));
typedef float f32x4 __attribute__((ext_vector_type(4)));
typedef short s16x4 __attribute__((ext_vector_type(4)));
typedef unsigned short u16;
typedef unsigned int u32;

__device__ __forceinline__ u16 f2bf(float f) {
  union { __bf16 h; u16 s; } u; u.h = (__bf16)f; return u.s;
}
__device__ __forceinline__ float bf2f(u16 v) {
  union { u32 u; float f; } x; x.u = (u32)v << 16; return x.f;
}
__device__ __forceinline__ u32 pk2(float a, float b) {
  return (u32)f2bf(a) | ((u32)f2bf(b) << 16);
}

// ---------------- x transpose: fp32 [b][c][n] -> bf16 [b][n][256] ----------------
__global__ __launch_bounds__(256) void xt_kernel(
    const float* __restrict__ x, u16* __restrict__ xT)
{
  const int b = blockIdx.z, c0 = blockIdx.y * 64, n0 = blockIdx.x * 64;
  __shared__ __align__(16) float T[64][68];
  const int t = threadIdx.x;
  {
    const int cr = t >> 4, nc = (t & 15) * 4;
    #pragma unroll
    for (int ci = 0; ci < 4; ++ci) {
      const float4 v = *(const float4*)&x[((size_t)(b * CDIM + c0 + cr + ci * 16)) * NDIM + n0 + nc];
      *(float4*)&T[cr + ci * 16][nc] = v;
    }
  }
  __syncthreads();
  {
    const int n = t >> 2, g = t & 3;
    union { u16 u[16]; uint4 v[2]; } pk;
    #pragma unroll
    for (int u_ = 0; u_ < 16; ++u_) pk.u[u_] = f2bf(T[g * 16 + u_][n]);
    uint4* dst = (uint4*)&xT[((size_t)(b * NDIM + n0 + n)) * CDIM + c0 + g * 16];
    dst[0] = pk.v[0]; dst[1] = pk.v[1];
  }
}

// ---------------- fused Q/K/V projection (o-tile 128) ----------------
// Grid (NDIM/64, 6, BDIM): p = y>>1, o0 = (y&1)*128.
// Q/K -> bf16 [b][n][256] head-major (Q scaled log2e/8 incl bias);
// V -> bf16 [b][c][n]. Weights read fp32, converted inline.
__global__ __launch_bounds__(256, 4) void qkv_kernel(
    const u16* __restrict__ xT,
    const float* __restrict__ wq, const float* __restrict__ bq,
    const float* __restrict__ wk, const float* __restrict__ bk,
    const float* __restrict__ wv, const float* __restrict__ bv,
    u16* __restrict__ qT, u16* __restrict__ kT, u16* __restrict__ vB)
{
  const int b = blockIdx.z;
  const int p = blockIdx.y >> 1;
  const int o0 = (blockIdx.y & 1) * 128;
  const int n0 = blockIdx.x * 64;
  const float* wsel = (p == 0) ? wq : (p == 1) ? wk : wv;
  const float* bsel = (p == 0) ? bq : (p == 1) ? bk : bv;
  const float wscale = (p == 0) ? QSCALE : 1.0f;

  __shared__ __align__(16) u16 XTs[64][40];
  __shared__ __align__(16) u16 Ws[128][40];
  const int t = threadIdx.x, lane = t & 63, w = t >> 6;
  const int qd = lane >> 4, lm = lane & 15;
  const int sr = t >> 2, sg = (t & 3) * 8;
  const int r2 = t >> 1, g2 = (t & 1) * 16;

  const u16* xsrc = xT + ((size_t)(b * NDIM + n0 + sr)) * CDIM + sg;
  const float* wsrc = wsel + (size_t)(o0 + r2) * CDIM + g2;

  f32x4 acc[4][2];
  #pragma unroll
  for (int nt = 0; nt < 4; ++nt)
    #pragma unroll
    for (int j = 0; j < 2; ++j) acc[nt][j] = (f32x4){0.f, 0.f, 0.f, 0.f};

  for (int cs = 0; cs < 8; ++cs) {
    __syncthreads();
    *(uint4*)&XTs[sr][sg] = *(const uint4*)(xsrc + cs * 32);
    {
      const float4 w0 = *(const float4*)(wsrc + cs * 32);
      const float4 w1 = *(const float4*)(wsrc + cs * 32 + 4);
      const float4 w2 = *(const float4*)(wsrc + cs * 32 + 8);
      const float4 w3 = *(const float4*)(wsrc + cs * 32 + 12);
      union { u32 p[8]; uint4 v[2]; } pw;
      pw.p[0] = pk2(w0.x * wscale, w0.y * wscale);
      pw.p[1] = pk2(w0.z * wscale, w0.w * wscale);
      pw.p[2] = pk2(w1.x * wscale, w1.y * wscale);
      pw.p[3] = pk2(w1.z * wscale, w1.w * wscale);
      pw.p[4] = pk2(w2.x * wscale, w2.y * wscale);
      pw.p[5] = pk2(w2.z * wscale, w2.w * wscale);
      pw.p[6] = pk2(w3.x * wscale, w3.y * wscale);
      pw.p[7] = pk2(w3.z * wscale, w3.w * wscale);
      *(uint4*)&Ws[r2][g2]     = pw.v[0];
      *(uint4*)&Ws[r2][g2 + 8] = pw.v[1];
    }
    __syncthreads();
    bf16x8 xf[4], wf[2];
    #pragma unroll
    for (int nt = 0; nt < 4; ++nt) xf[nt] = *(const bf16x8*)&XTs[16 * nt + lm][qd * 8];
    #pragma unroll
    for (int j = 0; j < 2; ++j) wf[j] = *(const bf16x8*)&Ws[32 * w + 16 * j + lm][qd * 8];
    #pragma unroll
    for (int nt = 0; nt < 4; ++nt)
      #pragma unroll
      for (int j = 0; j < 2; ++j) {
        if (p < 2)
          acc[nt][j] = __builtin_amdgcn_mfma_f32_16x16x32_bf16(xf[nt], wf[j], acc[nt][j], 0, 0, 0);
        else
          acc[nt][j] = __builtin_amdgcn_mfma_f32_16x16x32_bf16(wf[j], xf[nt], acc[nt][j], 0, 0, 0);
      }
  }

  if (p < 2) {
    // D[m=n][col=o]: n = n0+16nt+4qd+r, o = o0+32w+16j+lm
    u16* out = (p == 0) ? qT : kT;
    #pragma unroll
    for (int j = 0; j < 2; ++j) {
      const int og = o0 + 32 * w + 16 * j + lm;
      const float bv2 = bsel[og] * wscale;
      #pragma unroll
      for (int nt = 0; nt < 4; ++nt)
        #pragma unroll
        for (int r = 0; r < 4; ++r) {
          const int n = n0 + 16 * nt + 4 * qd + r;
          out[((size_t)(b * NDIM + n)) * CDIM + og] = f2bf(acc[nt][j][r] + bv2);
        }
    }
  } else {
    // D[m=o][col=n]: o = o0+32w+16j+4qd+r, n = n0+16nt+lm
    #pragma unroll
    for (int j = 0; j < 2; ++j) {
      const float4 b4 = *(const float4*)&bsel[o0 + 32 * w + 16 * j + 4 * qd];
      const float bvr[4] = {b4.x, b4.y, b4.z, b4.w};
      #pragma unroll
      for (int nt = 0; nt < 4; ++nt)
        #pragma unroll
        for (int r = 0; r < 4; ++r) {
          const int og = o0 + 32 * w + 16 * j + 4 * qd + r;
          const int n = n0 + 16 * nt + lm;
          vB[((size_t)(b * CDIM + og)) * NDIM + n] = f2bf(acc[nt][j][r] + bvr[r]);
        }
    }
  }
}

// ---------------- K-split(4) S^T-form MFMA flash attention ----------------
// Single 18KB K/V LDS buffer (8 blocks/CU) + depth-1 register prefetch.
// Per 64-key tile: issue next tile's global loads -> barrier -> compute ->
// barrier -> write prefetched regs to LDS.
__global__ __launch_bounds__(256, 4) void attn_kernel(
    const u16* __restrict__ qT, const u16* __restrict__ kT,
    const u16* __restrict__ vB, u16* __restrict__ Opart,
    float* __restrict__ Lp)
{
  const int bh = blockIdx.y, b = bh >> 2, h = bh & 3;
  const int n0 = blockIdx.x * 128;
  const int z  = blockIdx.z;

  // [0]=K tile, [1]=V tile. 2*64*72*2B = 18432 B -> 8 blocks/CU.
  __shared__ __align__(16) u16 KV[2][64][72];

  const int t = threadIdx.x, lane = t & 63, w = t >> 6;
  const int qd = lane >> 4, lm = lane & 15;

  // Q fragments straight from global: rows are wave-private, read once.
  bf16x8 qf[2][2];
  {
    const u16* qbase = qT + ((size_t)(b * NDIM) + n0) * CDIM + h * 64;
    #pragma unroll
    for (int s = 0; s < 2; ++s)
      #pragma unroll
      for (int hh = 0; hh < 2; ++hh)
        qf[s][hh] = *(const bf16x8*)(qbase +
            (size_t)(16 * (2 * w + s) + lm) * CDIM + 32 * hh + qd * 8);
  }

  float l_i[2] = {0.f, 0.f};
  f32x4 oa[2][4];
  #pragma unroll
  for (int s = 0; s < 2; ++s)
    #pragma unroll
    for (int dt = 0; dt < 4; ++dt) oa[s][dt] = (f32x4){0.f, 0.f, 0.f, 0.f};

  const int sr = t >> 2, sg = (t & 3) * 16;
  const u16* kptr = kT + ((size_t)(b * NDIM) + z * KPERZ + sr) * CDIM + h * 64 + sg;
  const u16* vptr = vB + ((size_t)(b * CDIM) + h * 64 + sr) * NDIM + z * KPERZ + sg;

  // prologue: stage tile 0
  {
    const uint4 ka0 = *(const uint4*)(kptr);
    const uint4 kb0 = *(const uint4*)(kptr + 8);
    const uint4 va0 = *(const uint4*)(vptr);
    const uint4 vv0 = *(const uint4*)(vptr + 8);
    kptr += (size_t)64 * CDIM;
    vptr += 64;
    uint4* kd = (uint4*)&KV[0][sr][sg]; kd[0] = ka0; kd[1] = kb0;
    uint4* vd = (uint4*)&KV[1][sr][sg]; vd[0] = va0; vd[1] = vv0;
  }

  uint4 ka, kb, va, vv;
  #pragma unroll 1
  for (int it = 0; it < KPERZ / 64; ++it) {
    const bool pf = (it + 1 < KPERZ / 64);
    if (pf) {
      // issue next tile's loads now; latency hides under this tile's compute
      ka = *(const uint4*)(kptr);
      kb = *(const uint4*)(kptr + 8);
      va = *(const uint4*)(vptr);
      vv = *(const uint4*)(vptr + 8);
      kptr += (size_t)64 * CDIM;
      vptr += 64;
    }
    __builtin_amdgcn_sched_barrier(0);   // pin load issue before compute
    __syncthreads();                     // tile it's LDS writes visible

    // P fragments, packed bf16 at production: pk[s][c].v is the PV B-operand
    union { u16 u[4]; s16x4 v; } pk[2][4];
    float rs[2] = {0.f, 0.f};

    #pragma unroll
    for (int nt = 0; nt < 4; ++nt) {
      const bf16x8 kf0 = *(const bf16x8*)&KV[0][16 * nt + lm][qd * 8];
      const bf16x8 kf1 = *(const bf16x8*)&KV[0][16 * nt + lm][32 + qd * 8];
      #pragma unroll
      for (int s = 0; s < 2; ++s) {
        f32x4 zz = (f32x4){0.f, 0.f, 0.f, 0.f};
        __builtin_amdgcn_s_setprio(1);
        zz = __builtin_amdgcn_mfma_f32_16x16x32_bf16(kf0, qf[s][0], zz, 0, 0, 0);
        zz = __builtin_amdgcn_mfma_f32_16x16x32_bf16(kf1, qf[s][1], zz, 0, 0, 0);
        __builtin_amdgcn_s_setprio(0);
        #pragma unroll
        for (int r = 0; r < 4; ++r) {
          const float p = __builtin_amdgcn_exp2f(zz[r]);
          pk[s][nt].u[r] = f2bf(p);
          rs[s] += p;
        }
      }
    }
    l_i[0] += rs[0];
    l_i[1] += rs[1];

    #pragma unroll
    for (int c = 0; c < 4; ++c) {
      s16x4 av[4];
      #pragma unroll
      for (int dt = 0; dt < 4; ++dt)
        av[dt] = *(const s16x4*)&KV[1][16 * dt + lm][16 * c + 4 * qd];
      __builtin_amdgcn_s_setprio(1);
      #pragma unroll
      for (int dt = 0; dt < 4; ++dt) {
        oa[0][dt] = __builtin_amdgcn_mfma_f32_16x16x16bf16_1k(av[dt], pk[0][c].v, oa[0][dt], 0, 0, 0);
        oa[1][dt] = __builtin_amdgcn_mfma_f32_16x16x16bf16_1k(av[dt], pk[1][c].v, oa[1][dt], 0, 0, 0);
      }
      __builtin_amdgcn_s_setprio(0);
    }

    __syncthreads();                     // all reads of tile it done
    if (pf) {
      // stage next tile (vmcnt wait is ~free: loads issued a full tile ago)
      uint4* kd = (uint4*)&KV[0][sr][sg]; kd[0] = ka; kd[1] = kb;
      uint4* vd = (uint4*)&KV[1][sr][sg]; vd[0] = va; vd[1] = vv;
    }
  }

  // deferred l reduction across the 4 quads (lane bits 4,5)
  #pragma unroll
  for (int s = 0; s < 2; ++s) {
    l_i[s] += __shfl_xor(l_i[s], 16);
    l_i[s] += __shfl_xor(l_i[s], 32);
  }

  // epilogue: normalize, transpose via LDS (overlay K/V region), write rows.
  // Loop's final barrier already separates last tile's reads from this overlay.
  u16 (*Ot)[72] = (u16(*)[72])&KV[0][0][0];   // [128][72] == 2*64*72 exactly
  #pragma unroll
  for (int s = 0; s < 2; ++s) {
    const float inv = 1.0f / l_i[s];
    #pragma unroll
    for (int dt = 0; dt < 4; ++dt)
      #pragma unroll
      for (int r = 0; r < 4; ++r)
        Ot[16 * (2 * w + s) + lm][16 * dt + 4 * qd + r] = f2bf(oa[s][dt][r] * inv);
  }
  if (qd == 0) {
    const size_t lbase = ((size_t)z * (BDIM * HDIM) + bh) * NDIM;
    #pragma unroll
    for (int s = 0; s < 2; ++s)
      Lp[lbase + n0 + 16 * (2 * w + s) + lm] = l_i[s];
  }
  __syncthreads();
  {
    const int r = t >> 1, g = (t & 1) * 32;
    u16* dst = Opart + (((size_t)z * (BDIM * HDIM) + bh) * NDIM + n0 + r) * DKDIM + g;
    const uint4* srcp = (const uint4*)&Ot[r][g];
    uint4* d4 = (uint4*)dst;
    d4[0] = srcp[0]; d4[1] = srcp[1]; d4[2] = srcp[2]; d4[3] = srcp[3];
  }
}

// ---------------- output projection, o-tile 128, fused 4-way combine ----------------
// Grid (NDIM/64, 2, BDIM). Combine weights = l ratios (shift-free partials).
__global__ __launch_bounds__(256, 4) void projout_kernel(
    const u16* __restrict__ Opart, const float* __restrict__ Lp,
    const float* __restrict__ wp, const float* __restrict__ bp,
    const float* __restrict__ res, float* __restrict__ out)
{
  const int b = blockIdx.z, o0 = blockIdx.y * 128, n0 = blockIdx.x * 64;
  __shared__ __align__(16) u16 XTs[64][40];
  __shared__ __align__(16) u16 Ws[128][40];
  const int t = threadIdx.x, lane = t & 63, w = t >> 6;
  const int qd = lane >> 4, lm = lane & 15;
  const int sr = t >> 2, sg = (t & 3) * 8;
  const int r2 = t >> 1, g2 = (t & 1) * 16;

  float wh[4][NSPLIT];
  #pragma unroll
  for (int hh = 0; hh < 4; ++hh) {
    const size_t i0 = ((size_t)(b * HDIM + hh)) * NDIM + n0 + sr;
    float l[NSPLIT], tot = 0.f;
    #pragma unroll
    for (int zz = 0; zz < NSPLIT; ++zz) { l[zz] = Lp[(size_t)zz * NQ + i0]; tot += l[zz]; }
    const float iv = 1.0f / tot;
    #pragma unroll
    for (int zz = 0; zz < NSPLIT; ++zz) wh[hh][zz] = l[zz] * iv;
  }

  const float* wsrc = wp + (size_t)(o0 + r2) * CDIM + g2;

  f32x4 acc[4][2];
  #pragma unroll
  for (int nt = 0; nt < 4; ++nt)
    #pragma unroll
    for (int j = 0; j < 2; ++j) acc[nt][j] = (f32x4){0.f, 0.f, 0.f, 0.f};

  for (int cs = 0; cs < 8; ++cs) {
    const int c0 = cs * 32;
    const int hh = c0 >> 6;
    const int dk = (c0 & 63) + sg;
    __syncthreads();
    {
      const size_t obase = (((size_t)(b * HDIM + hh)) * NDIM + n0 + sr) * DKDIM + dk;
      float v[8] = {0.f, 0.f, 0.f, 0.f, 0.f, 0.f, 0.f, 0.f};
      #pragma unroll
      for (int zz = 0; zz < NSPLIT; ++zz) {
        union { u16 u[8]; uint4 q; } a;
        a.q = *(const uint4*)(Opart + (size_t)zz * NQ * DKDIM + obase);
        const float wz = wh[hh][zz];
        #pragma unroll
        for (int j = 0; j < 8; ++j) v[j] = fmaf(wz, bf2f(a.u[j]), v[j]);
      }
      union { u16 u[8]; uint4 q; } ov;
      #pragma unroll
      for (int j = 0; j < 8; ++j) ov.u[j] = f2bf(v[j]);
      *(uint4*)&XTs[sr][sg] = ov.q;
      const float4 wv0 = *(const float4*)(wsrc + c0);
      const float4 wv1 = *(const float4*)(wsrc + c0 + 4);
      const float4 wv2 = *(const float4*)(wsrc + c0 + 8);
      const float4 wv3 = *(const float4*)(wsrc + c0 + 12);
      union { u32 p[8]; uint4 v[2]; } pw;
      pw.p[0] = pk2(wv0.x, wv0.y); pw.p[1] = pk2(wv0.z, wv0.w);
      pw.p[2] = pk2(wv1.x, wv1.y); pw.p[3] = pk2(wv1.z, wv1.w);
      pw.p[4] = pk2(wv2.x, wv2.y); pw.p[5] = pk2(wv2.z, wv2.w);
      pw.p[6] = pk2(wv3.x, wv3.y); pw.p[7] = pk2(wv3.z, wv3.w);
      *(uint4*)&Ws[r2][g2]     = pw.v[0];
      *(uint4*)&Ws[r2][g2 + 8] = pw.v[1];
    }
    __syncthreads();
    bf16x8 xf[4], wf[2];
    #pragma unroll
    for (int nt = 0; nt < 4; ++nt) xf[nt] = *(const bf16x8*)&XTs[16 * nt + lm][qd * 8];
    #pragma unroll
    for (int j = 0; j < 2; ++j) wf[j] = *(const bf16x8*)&Ws[32 * w + 16 * j + lm][qd * 8];
    #pragma unroll
    for (int nt = 0; nt < 4; ++nt)
      #pragma unroll
      for (int j = 0; j < 2; ++j)
        acc[nt][j] = __builtin_amdgcn_mfma_f32_16x16x32_bf16(wf[j], xf[nt], acc[nt][j], 0, 0, 0);
  }

  // D[m=o][col=n]: o = o0+32w+16j+4qd+r, n = n0+16nt+lm
  #pragma unroll
  for (int j = 0; j < 2; ++j) {
    const float4 b4 = *(const float4*)&bp[o0 + 32 * w + 16 * j + 4 * qd];
    const float bvr[4] = {b4.x, b4.y, b4.z, b4.w};
    #pragma unroll
    for (int nt = 0; nt < 4; ++nt)
      #pragma unroll
      for (int r = 0; r < 4; ++r) {
        const int og = o0 + 32 * w + 16 * j + 4 * qd + r;
        const int n = n0 + 16 * nt + lm;
        const size_t idx = ((size_t)(b * CDIM + og)) * NDIM + n;
        out[idx] = acc[nt][j][r] + bvr[r] + res[idx];
      }
  }
}

extern "C" void kernel_launch(void* const* d_in, const int* in_sizes, int n_in,
                              void* d_out, int out_size, void* d_ws, size_t ws_size,
                              hipStream_t stream)
{
  const float* x  = (const float*)d_in[0];
  const float* wq = (const float*)d_in[1];
  const float* bq = (const float*)d_in[2];
  const float* wk = (const float*)d_in[3];
  const float* bk = (const float*)d_in[4];
  const float* wv = (const float*)d_in[5];
  const float* bv = (const float*)d_in[6];
  const float* wp = (const float*)d_in[7];
  const float* bp = (const float*)d_in[8];
  float* out = (float*)d_out;

  const size_t sz = (size_t)BDIM * CDIM * NDIM;   // 4.19M elements
  u16* xTb = (u16*)d_ws;
  u16* qTb = xTb + sz;
  u16* kTb = qTb + sz;
  u16* vBb = kTb + sz;
  u16* Opart = vBb + sz;                          // NSPLIT*sz u16
  float* Lp = (float*)(Opart + (size_t)NSPLIT * sz);  // NSPLIT*NQ floats

  const dim3 blk(256);
  xt_kernel<<<dim3(NDIM / 64, CDIM / 64, BDIM), blk, 0, stream>>>(x, xTb);
  qkv_kernel<<<dim3(NDIM / 64, 6, BDIM), blk, 0, stream>>>(
      xTb, wq, bq, wk, bk, wv, bv, qTb, kTb, vBb);
  attn_kernel<<<dim3(NDIM / 128, BDIM * HDIM, NSPLIT), blk, 0, stream>>>(
      qTb, kTb, vBb, Opart, Lp);
  projout_kernel<<<dim3(NDIM / 64, 2, BDIM), blk, 0, stream>>>(
      Opart, Lp, wp, bp, x, out);
}

// Round 5
// 202.154 us; speedup vs baseline: 1.0882x; 1.0510x over previous
//
#include <hip/hip_runtime.h>

// Attention_72902774882333 — R14: register-occupancy attack. R13 proved attn is
// capped at 3 blocks/CU by VGPR+AGPR total (~160/wave), NOT grid (NSPLIT=4 null)
// and NOT LDS. R14 removes the 16-VGPR register prefetch: K/V staged via
// global_load_lds (width16, zero data regs) into a double-buffered UNPADDED
// [2][2][64][64] 32KB LDS region, one barrier/tile (barrier's vmcnt(0) drain =
// counted wait; next tile's loads fly during compute). Bank conflicts on linear
// 128B rows fixed by XOR-16B-granule swizzle applied on BOTH sides (rule 21):
// source granule g^(r&7) folded into per-lane global addr, reads XOR'd same.
// setprio/sched_barrier dropped (null vs R10). xt/qkv/projout unchanged.
// B=4, C=256, N=4096, H=4, DK=64.

#define BDIM 4
#define CDIM 256
#define NDIM 4096
#define HDIM 4
#define DKDIM 64
#define NQ   (BDIM * HDIM * NDIM)       // 65536
#define NSPLIT 4
#define KPERZ (NDIM / NSPLIT)           // 1024 keys per split
#define QSCALE 0.18033688011112042f     // log2(e)/8

typedef __bf16 bf16x8 __attribute__((ext_vector_type(8)));
typedef float f32x4 __attribute__((ext_vector_type(4)));
typedef short s16x4 __attribute__((ext_vector_type(4)));
typedef unsigned short u16;
typedef unsigned int u32;

__device__ __forceinline__ u16 f2bf(float f) {
  union { __bf16 h; u16 s; } u; u.h = (__bf16)f; return u.s;
}
__device__ __forceinline__ float bf2f(u16 v) {
  union { u32 u; float f; } x; x.u = (u32)v << 16; return x.f;
}
__device__ __forceinline__ u32 pk2(float a, float b) {
  return (u32)f2bf(a) | ((u32)f2bf(b) << 16);
}
__device__ __forceinline__ void gload16(const u16* g, u16* l) {
  __builtin_amdgcn_global_load_lds(
      (const __attribute__((address_space(1))) void*)g,
      (__attribute__((address_space(3))) void*)l, 16, 0, 0);
}

// ---------------- x transpose: fp32 [b][c][n] -> bf16 [b][n][256] ----------------
__global__ __launch_bounds__(256) void xt_kernel(
    const float* __restrict__ x, u16* __restrict__ xT)
{
  const int b = blockIdx.z, c0 = blockIdx.y * 64, n0 = blockIdx.x * 64;
  __shared__ __align__(16) float T[64][68];
  const int t = threadIdx.x;
  {
    const int cr = t >> 4, nc = (t & 15) * 4;
    #pragma unroll
    for (int ci = 0; ci < 4; ++ci) {
      const float4 v = *(const float4*)&x[((size_t)(b * CDIM + c0 + cr + ci * 16)) * NDIM + n0 + nc];
      *(float4*)&T[cr + ci * 16][nc] = v;
    }
  }
  __syncthreads();
  {
    const int n = t >> 2, g = t & 3;
    union { u16 u[16]; uint4 v[2]; } pk;
    #pragma unroll
    for (int u_ = 0; u_ < 16; ++u_) pk.u[u_] = f2bf(T[g * 16 + u_][n]);
    uint4* dst = (uint4*)&xT[((size_t)(b * NDIM + n0 + n)) * CDIM + c0 + g * 16];
    dst[0] = pk.v[0]; dst[1] = pk.v[1];
  }
}

// ---------------- fused Q/K/V projection (o-tile 128) ----------------
// Grid (NDIM/64, 6, BDIM): p = y>>1, o0 = (y&1)*128.
// Q/K -> bf16 [b][n][256] head-major (Q scaled log2e/8 incl bias);
// V -> bf16 [b][c][n]. Weights read fp32, converted inline.
__global__ __launch_bounds__(256, 4) void qkv_kernel(
    const u16* __restrict__ xT,
    const float* __restrict__ wq, const float* __restrict__ bq,
    const float* __restrict__ wk, const float* __restrict__ bk,
    const float* __restrict__ wv, const float* __restrict__ bv,
    u16* __restrict__ qT, u16* __restrict__ kT, u16* __restrict__ vB)
{
  const int b = blockIdx.z;
  const int p = blockIdx.y >> 1;
  const int o0 = (blockIdx.y & 1) * 128;
  const int n0 = blockIdx.x * 64;
  const float* wsel = (p == 0) ? wq : (p == 1) ? wk : wv;
  const float* bsel = (p == 0) ? bq : (p == 1) ? bk : bv;
  const float wscale = (p == 0) ? QSCALE : 1.0f;

  __shared__ __align__(16) u16 XTs[64][40];
  __shared__ __align__(16) u16 Ws[128][40];
  const int t = threadIdx.x, lane = t & 63, w = t >> 6;
  const int qd = lane >> 4, lm = lane & 15;
  const int sr = t >> 2, sg = (t & 3) * 8;
  const int r2 = t >> 1, g2 = (t & 1) * 16;

  const u16* xsrc = xT + ((size_t)(b * NDIM + n0 + sr)) * CDIM + sg;
  const float* wsrc = wsel + (size_t)(o0 + r2) * CDIM + g2;

  f32x4 acc[4][2];
  #pragma unroll
  for (int nt = 0; nt < 4; ++nt)
    #pragma unroll
    for (int j = 0; j < 2; ++j) acc[nt][j] = (f32x4){0.f, 0.f, 0.f, 0.f};

  for (int cs = 0; cs < 8; ++cs) {
    __syncthreads();
    *(uint4*)&XTs[sr][sg] = *(const uint4*)(xsrc + cs * 32);
    {
      const float4 w0 = *(const float4*)(wsrc + cs * 32);
      const float4 w1 = *(const float4*)(wsrc + cs * 32 + 4);
      const float4 w2 = *(const float4*)(wsrc + cs * 32 + 8);
      const float4 w3 = *(const float4*)(wsrc + cs * 32 + 12);
      union { u32 p[8]; uint4 v[2]; } pw;
      pw.p[0] = pk2(w0.x * wscale, w0.y * wscale);
      pw.p[1] = pk2(w0.z * wscale, w0.w * wscale);
      pw.p[2] = pk2(w1.x * wscale, w1.y * wscale);
      pw.p[3] = pk2(w1.z * wscale, w1.w * wscale);
      pw.p[4] = pk2(w2.x * wscale, w2.y * wscale);
      pw.p[5] = pk2(w2.z * wscale, w2.w * wscale);
      pw.p[6] = pk2(w3.x * wscale, w3.y * wscale);
      pw.p[7] = pk2(w3.z * wscale, w3.w * wscale);
      *(uint4*)&Ws[r2][g2]     = pw.v[0];
      *(uint4*)&Ws[r2][g2 + 8] = pw.v[1];
    }
    __syncthreads();
    bf16x8 xf[4], wf[2];
    #pragma unroll
    for (int nt = 0; nt < 4; ++nt) xf[nt] = *(const bf16x8*)&XTs[16 * nt + lm][qd * 8];
    #pragma unroll
    for (int j = 0; j < 2; ++j) wf[j] = *(const bf16x8*)&Ws[32 * w + 16 * j + lm][qd * 8];
    #pragma unroll
    for (int nt = 0; nt < 4; ++nt)
      #pragma unroll
      for (int j = 0; j < 2; ++j) {
        if (p < 2)
          acc[nt][j] = __builtin_amdgcn_mfma_f32_16x16x32_bf16(xf[nt], wf[j], acc[nt][j], 0, 0, 0);
        else
          acc[nt][j] = __builtin_amdgcn_mfma_f32_16x16x32_bf16(wf[j], xf[nt], acc[nt][j], 0, 0, 0);
      }
  }

  if (p < 2) {
    // D[m=n][col=o]: n = n0+16nt+4qd+r, o = o0+32w+16j+lm
    u16* out = (p == 0) ? qT : kT;
    #pragma unroll
    for (int j = 0; j < 2; ++j) {
      const int og = o0 + 32 * w + 16 * j + lm;
      const float bv2 = bsel[og] * wscale;
      #pragma unroll
      for (int nt = 0; nt < 4; ++nt)
        #pragma unroll
        for (int r = 0; r < 4; ++r) {
          const int n = n0 + 16 * nt + 4 * qd + r;
          out[((size_t)(b * NDIM + n)) * CDIM + og] = f2bf(acc[nt][j][r] + bv2);
        }
    }
  } else {
    // D[m=o][col=n]: o = o0+32w+16j+4qd+r, n = n0+16nt+lm
    #pragma unroll
    for (int j = 0; j < 2; ++j) {
      const float4 b4 = *(const float4*)&bsel[o0 + 32 * w + 16 * j + 4 * qd];
      const float bvr[4] = {b4.x, b4.y, b4.z, b4.w};
      #pragma unroll
      for (int nt = 0; nt < 4; ++nt)
        #pragma unroll
        for (int r = 0; r < 4; ++r) {
          const int og = o0 + 32 * w + 16 * j + 4 * qd + r;
          const int n = n0 + 16 * nt + lm;
          vB[((size_t)(b * CDIM + og)) * NDIM + n] = f2bf(acc[nt][j][r] + bvr[r]);
        }
    }
  }
}

// ---------------- K-split(4) S^T-form MFMA flash attention ----------------
// global_load_lds staging, double-buffered 32KB LDS, 1 barrier/tile,
// XOR-16B-granule swizzle (source+read) for conflict-free unpadded rows.
__global__ __launch_bounds__(256, 4) void attn_kernel(
    const u16* __restrict__ qT, const u16* __restrict__ kT,
    const u16* __restrict__ vB, u16* __restrict__ Opart,
    float* __restrict__ Lp)
{
  const int bh = blockIdx.y, b = bh >> 2, h = bh & 3;
  const int n0 = blockIdx.x * 128;
  const int z  = blockIdx.z;

  // [buf][0]=K tile, [buf][1]=V tile. 2*2*64*64*2B = 32768 B.
  __shared__ __align__(16) u16 KVlds[2][2][64][64];

  const int t = threadIdx.x, lane = t & 63, w = t >> 6;
  const int qd = lane >> 4, lm = lane & 15, l7 = lm & 7;

  // Q fragments straight from global: rows are wave-private, read once.
  bf16x8 qf[2][2];
  {
    const u16* qbase = qT + ((size_t)(b * NDIM) + n0) * CDIM + h * 64;
    #pragma unroll
    for (int s = 0; s < 2; ++s)
      #pragma unroll
      for (int hh = 0; hh < 2; ++hh)
        qf[s][hh] = *(const bf16x8*)(qbase +
            (size_t)(16 * (2 * w + s) + lm) * CDIM + 32 * hh + qd * 8);
  }

  float l_i[2] = {0.f, 0.f};
  f32x4 oa[2][4];
  #pragma unroll
  for (int s = 0; s < 2; ++s)
    #pragma unroll
    for (int dt = 0; dt < 4; ++dt) oa[s][dt] = (f32x4){0.f, 0.f, 0.f, 0.f};

  // staging: wave w, issue i covers LDS rows 8*(4i+w)..+8; lane -> row 8*(4i+w)+(lane>>3),
  // 16B granule (lane&7), source granule pre-swizzled: ^(row&7) = ^(lane>>3).
  const int srow = lane >> 3;
  const int swz  = 8 * ((lane & 7) ^ srow);       // elems
  const u16* kp0 = kT + ((size_t)(b * NDIM + z * KPERZ + 8 * w + srow)) * CDIM + h * 64 + swz;
  const u16* kp1 = kp0 + (size_t)32 * CDIM;
  const u16* vp0 = vB + ((size_t)(b * CDIM + h * 64 + 8 * w + srow)) * NDIM + z * KPERZ + swz;
  const u16* vp1 = vp0 + (size_t)32 * NDIM;

  // prologue: stage tile 0 into buf 0
  {
    u16* kb = &KVlds[0][0][0][0];
    u16* vb2 = &KVlds[0][1][0][0];
    gload16(kp0, kb + w * 512);
    gload16(kp1, kb + (4 + w) * 512);
    gload16(vp0, vb2 + w * 512);
    gload16(vp1, vb2 + (4 + w) * 512);
  }

  #pragma unroll 1
  for (int it = 0; it < KPERZ / 64; ++it) {
    __syncthreads();   // vmcnt(0) drain: tile 'it' landed; all waves synced
    if (it + 1 < KPERZ / 64) {
      // issue next tile into the other buffer; lands by next barrier
      const size_t ko = (size_t)(it + 1) * 64 * CDIM;
      const int    vo = (it + 1) * 64;
      u16* kb = &KVlds[(it + 1) & 1][0][0][0];
      u16* vb2 = &KVlds[(it + 1) & 1][1][0][0];
      gload16(kp0 + ko, kb + w * 512);
      gload16(kp1 + ko, kb + (4 + w) * 512);
      gload16(vp0 + vo, vb2 + w * 512);
      gload16(vp1 + vo, vb2 + (4 + w) * 512);
    }
    const u16 (*Kt)[64] = KVlds[it & 1][0];
    const u16 (*Vt)[64] = KVlds[it & 1][1];

    // P fragments, packed bf16 at production: pk[s][c].v is the PV B-operand
    union { u16 u[4]; s16x4 v; } pk[2][4];
    float rs[2] = {0.f, 0.f};

    #pragma unroll
    for (int nt = 0; nt < 4; ++nt) {
      // swizzled read: granule (4hh+qd) ^ (row&7), row&7 == lm&7
      const bf16x8 kf0 = *(const bf16x8*)&Kt[16 * nt + lm][8 * (qd ^ l7)];
      const bf16x8 kf1 = *(const bf16x8*)&Kt[16 * nt + lm][8 * ((4 + qd) ^ l7)];
      #pragma unroll
      for (int s = 0; s < 2; ++s) {
        f32x4 zz = (f32x4){0.f, 0.f, 0.f, 0.f};
        zz = __builtin_amdgcn_mfma_f32_16x16x32_bf16(kf0, qf[s][0], zz, 0, 0, 0);
        zz = __builtin_amdgcn_mfma_f32_16x16x32_bf16(kf1, qf[s][1], zz, 0, 0, 0);
        #pragma unroll
        for (int r = 0; r < 4; ++r) {
          const float p = __builtin_amdgcn_exp2f(zz[r]);
          pk[s][nt].u[r] = f2bf(p);
          rs[s] += p;
        }
      }
    }
    l_i[0] += rs[0];
    l_i[1] += rs[1];

    #pragma unroll
    for (int c = 0; c < 4; ++c) {
      s16x4 av[4];
      #pragma unroll
      for (int dt = 0; dt < 4; ++dt)
        av[dt] = *(const s16x4*)&Vt[16 * dt + lm][(16 * c + 4 * qd) ^ (8 * l7)];
      #pragma unroll
      for (int dt = 0; dt < 4; ++dt) {
        oa[0][dt] = __builtin_amdgcn_mfma_f32_16x16x16bf16_1k(av[dt], pk[0][c].v, oa[0][dt], 0, 0, 0);
        oa[1][dt] = __builtin_amdgcn_mfma_f32_16x16x16bf16_1k(av[dt], pk[1][c].v, oa[1][dt], 0, 0, 0);
      }
    }
  }

  // deferred l reduction across the 4 quads (lane bits 4,5)
  #pragma unroll
  for (int s = 0; s < 2; ++s) {
    l_i[s] += __shfl_xor(l_i[s], 16);
    l_i[s] += __shfl_xor(l_i[s], 32);
  }

  __syncthreads();   // all waves done reading the last tile before overlay
  // epilogue: normalize, transpose via LDS (overlay KV region), write rows.
  u16 (*Ot)[72] = (u16(*)[72])&KVlds[0][0][0][0];   // [128][72] = 18432B fits
  #pragma unroll
  for (int s = 0; s < 2; ++s) {
    const float inv = 1.0f / l_i[s];
    #pragma unroll
    for (int dt = 0; dt < 4; ++dt)
      #pragma unroll
      for (int r = 0; r < 4; ++r)
        Ot[16 * (2 * w + s) + lm][16 * dt + 4 * qd + r] = f2bf(oa[s][dt][r] * inv);
  }
  if (qd == 0) {
    const size_t lbase = ((size_t)z * (BDIM * HDIM) + bh) * NDIM;
    #pragma unroll
    for (int s = 0; s < 2; ++s)
      Lp[lbase + n0 + 16 * (2 * w + s) + lm] = l_i[s];
  }
  __syncthreads();
  {
    const int r = t >> 1, g = (t & 1) * 32;
    u16* dst = Opart + (((size_t)z * (BDIM * HDIM) + bh) * NDIM + n0 + r) * DKDIM + g;
    const uint4* srcp = (const uint4*)&Ot[r][g];
    uint4* d4 = (uint4*)dst;
    d4[0] = srcp[0]; d4[1] = srcp[1]; d4[2] = srcp[2]; d4[3] = srcp[3];
  }
}

// ---------------- output projection, o-tile 128, fused 4-way combine ----------------
// Grid (NDIM/64, 2, BDIM). Combine weights = l ratios (shift-free partials).
__global__ __launch_bounds__(256, 4) void projout_kernel(
    const u16* __restrict__ Opart, const float* __restrict__ Lp,
    const float* __restrict__ wp, const float* __restrict__ bp,
    const float* __restrict__ res, float* __restrict__ out)
{
  const int b = blockIdx.z, o0 = blockIdx.y * 128, n0 = blockIdx.x * 64;
  __shared__ __align__(16) u16 XTs[64][40];
  __shared__ __align__(16) u16 Ws[128][40];
  const int t = threadIdx.x, lane = t & 63, w = t >> 6;
  const int qd = lane >> 4, lm = lane & 15;
  const int sr = t >> 2, sg = (t & 3) * 8;
  const int r2 = t >> 1, g2 = (t & 1) * 16;

  float wh[4][NSPLIT];
  #pragma unroll
  for (int hh = 0; hh < 4; ++hh) {
    const size_t i0 = ((size_t)(b * HDIM + hh)) * NDIM + n0 + sr;
    float l[NSPLIT], tot = 0.f;
    #pragma unroll
    for (int zz = 0; zz < NSPLIT; ++zz) { l[zz] = Lp[(size_t)zz * NQ + i0]; tot += l[zz]; }
    const float iv = 1.0f / tot;
    #pragma unroll
    for (int zz = 0; zz < NSPLIT; ++zz) wh[hh][zz] = l[zz] * iv;
  }

  const float* wsrc = wp + (size_t)(o0 + r2) * CDIM + g2;

  f32x4 acc[4][2];
  #pragma unroll
  for (int nt = 0; nt < 4; ++nt)
    #pragma unroll
    for (int j = 0; j < 2; ++j) acc[nt][j] = (f32x4){0.f, 0.f, 0.f, 0.f};

  for (int cs = 0; cs < 8; ++cs) {
    const int c0 = cs * 32;
    const int hh = c0 >> 6;
    const int dk = (c0 & 63) + sg;
    __syncthreads();
    {
      const size_t obase = (((size_t)(b * HDIM + hh)) * NDIM + n0 + sr) * DKDIM + dk;
      float v[8] = {0.f, 0.f, 0.f, 0.f, 0.f, 0.f, 0.f, 0.f};
      #pragma unroll
      for (int zz = 0; zz < NSPLIT; ++zz) {
        union { u16 u[8]; uint4 q; } a;
        a.q = *(const uint4*)(Opart + (size_t)zz * NQ * DKDIM + obase);
        const float wz = wh[hh][zz];
        #pragma unroll
        for (int j = 0; j < 8; ++j) v[j] = fmaf(wz, bf2f(a.u[j]), v[j]);
      }
      union { u16 u[8]; uint4 q; } ov;
      #pragma unroll
      for (int j = 0; j < 8; ++j) ov.u[j] = f2bf(v[j]);
      *(uint4*)&XTs[sr][sg] = ov.q;
      const float4 wv0 = *(const float4*)(wsrc + c0);
      const float4 wv1 = *(const float4*)(wsrc + c0 + 4);
      const float4 wv2 = *(const float4*)(wsrc + c0 + 8);
      const float4 wv3 = *(const float4*)(wsrc + c0 + 12);
      union { u32 p[8]; uint4 v[2]; } pw;
      pw.p[0] = pk2(wv0.x, wv0.y); pw.p[1] = pk2(wv0.z, wv0.w);
      pw.p[2] = pk2(wv1.x, wv1.y); pw.p[3] = pk2(wv1.z, wv1.w);
      pw.p[4] = pk2(wv2.x, wv2.y); pw.p[5] = pk2(wv2.z, wv2.w);
      pw.p[6] = pk2(wv3.x, wv3.y); pw.p[7] = pk2(wv3.z, wv3.w);
      *(uint4*)&Ws[r2][g2]     = pw.v[0];
      *(uint4*)&Ws[r2][g2 + 8] = pw.v[1];
    }
    __syncthreads();
    bf16x8 xf[4], wf[2];
    #pragma unroll
    for (int nt = 0; nt < 4; ++nt) xf[nt] = *(const bf16x8*)&XTs[16 * nt + lm][qd * 8];
    #pragma unroll
    for (int j = 0; j < 2; ++j) wf[j] = *(const bf16x8*)&Ws[32 * w + 16 * j + lm][qd * 8];
    #pragma unroll
    for (int nt = 0; nt < 4; ++nt)
      #pragma unroll
      for (int j = 0; j < 2; ++j)
        acc[nt][j] = __builtin_amdgcn_mfma_f32_16x16x32_bf16(wf[j], xf[nt], acc[nt][j], 0, 0, 0);
  }

  // D[m=o][col=n]: o = o0+32w+16j+4qd+r, n = n0+16nt+lm
  #pragma unroll
  for (int j = 0; j < 2; ++j) {
    const float4 b4 = *(const float4*)&bp[o0 + 32 * w + 16 * j + 4 * qd];
    const float bvr[4] = {b4.x, b4.y, b4.z, b4.w};
    #pragma unroll
    for (int nt = 0; nt < 4; ++nt)
      #pragma unroll
      for (int r = 0; r < 4; ++r) {
        const int og = o0 + 32 * w + 16 * j + 4 * qd + r;
        const int n = n0 + 16 * nt + lm;
        const size_t idx = ((size_t)(b * CDIM + og)) * NDIM + n;
        out[idx] = acc[nt][j][r] + bvr[r] + res[idx];
      }
  }
}

extern "C" void kernel_launch(void* const* d_in, const int* in_sizes, int n_in,
                              void* d_out, int out_size, void* d_ws, size_t ws_size,
                              hipStream_t stream)
{
  const float* x  = (const float*)d_in[0];
  const float* wq = (const float*)d_in[1];
  const float* bq = (const float*)d_in[2];
  const float* wk = (const float*)d_in[3];
  const float* bk = (const float*)d_in[4];
  const float* wv = (const float*)d_in[5];
  const float* bv = (const float*)d_in[6];
  const float* wp = (const float*)d_in[7];
  const float* bp = (const float*)d_in[8];
  float* out = (float*)d_out;

  const size_t sz = (size_t)BDIM * CDIM * NDIM;   // 4.19M elements
  u16* xTb = (u16*)d_ws;
  u16* qTb = xTb + sz;
  u16* kTb = qTb + sz;
  u16* vBb = kTb + sz;
  u16* Opart = vBb + sz;                          // NSPLIT*sz u16
  float* Lp = (float*)(Opart + (size_t)NSPLIT * sz);  // NSPLIT*NQ floats

  const dim3 blk(256);
  xt_kernel<<<dim3(NDIM / 64, CDIM / 64, BDIM), blk, 0, stream>>>(x, xTb);
  qkv_kernel<<<dim3(NDIM / 64, 6, BDIM), blk, 0, stream>>>(
      xTb, wq, bq, wk, bk, wv, bv, qTb, kTb, vBb);
  attn_kernel<<<dim3(NDIM / 128, BDIM * HDIM, NSPLIT), blk, 0, stream>>>(
      qTb, kTb, vBb, Opart, Lp);
  projout_kernel<<<dim3(NDIM / 64, 2, BDIM), blk, 0, stream>>>(
      Opart, Lp, wp, bp, x, out);
}

// Round 6
// 198.336 us; speedup vs baseline: 1.1091x; 1.0192x over previous
//
#include <hip/hip_runtime.h>

// Attention_72902774882333 — R15: non-attn harvest. attn (96.7µs, R14 body)
// kept byte-identical; NSPLIT back to 2 (R13 proved split-4 null for occupancy,
// costs partial-traffic). NEW: wconv kernel pre-converts wq/wk/wv/wp fp32->bf16
// once (QSCALE baked into wq); qkv/projout read W MFMA fragments DIRECTLY from
// global bf16 (L2-resident 512KB) — Ws LDS staging + per-block fp32->bf16 pack
// chain deleted (was ~32 VALU + 16 float4 loads + 10KB LDS per cs-step per
// block x 2048 blocks). B=4, C=256, N=4096, H=4, DK=64.

#define BDIM 4
#define CDIM 256
#define NDIM 4096
#define HDIM 4
#define DKDIM 64
#define NQ   (BDIM * HDIM * NDIM)       // 65536
#define NSPLIT 2
#define KPERZ (NDIM / NSPLIT)           // 2048 keys per split
#define QSCALE 0.18033688011112042f     // log2(e)/8
#define WSZ (CDIM * CDIM)               // 65536 elems per weight matrix

typedef __bf16 bf16x8 __attribute__((ext_vector_type(8)));
typedef float f32x4 __attribute__((ext_vector_type(4)));
typedef short s16x4 __attribute__((ext_vector_type(4)));
typedef unsigned short u16;
typedef unsigned int u32;

__device__ __forceinline__ u16 f2bf(float f) {
  union { __bf16 h; u16 s; } u; u.h = (__bf16)f; return u.s;
}
__device__ __forceinline__ float bf2f(u16 v) {
  union { u32 u; float f; } x; x.u = (u32)v << 16; return x.f;
}
__device__ __forceinline__ u32 pk2(float a, float b) {
  return (u32)f2bf(a) | ((u32)f2bf(b) << 16);
}
__device__ __forceinline__ void gload16(const u16* g, u16* l) {
  __builtin_amdgcn_global_load_lds(
      (const __attribute__((address_space(1))) void*)g,
      (__attribute__((address_space(3))) void*)l, 16, 0, 0);
}

// ---------------- weight conversion: fp32 -> bf16, once ----------------
// wb layout: [4][WSZ] = wq(scaled), wk, wv, wp. Grid (32, 4).
__global__ __launch_bounds__(256) void wconv_kernel(
    const float* __restrict__ wq, const float* __restrict__ wk,
    const float* __restrict__ wv, const float* __restrict__ wp,
    u16* __restrict__ wb)
{
  const int a = blockIdx.y;
  const float* src = (a == 0) ? wq : (a == 1) ? wk : (a == 2) ? wv : wp;
  const float sc = (a == 0) ? QSCALE : 1.0f;
  const int i = (blockIdx.x * 256 + threadIdx.x) * 8;
  const float4 v0 = *(const float4*)(src + i);
  const float4 v1 = *(const float4*)(src + i + 4);
  union { u32 p[4]; uint4 q; } o;
  o.p[0] = pk2(v0.x * sc, v0.y * sc);
  o.p[1] = pk2(v0.z * sc, v0.w * sc);
  o.p[2] = pk2(v1.x * sc, v1.y * sc);
  o.p[3] = pk2(v1.z * sc, v1.w * sc);
  *(uint4*)(wb + (size_t)a * WSZ + i) = o.q;
}

// ---------------- x transpose: fp32 [b][c][n] -> bf16 [b][n][256] ----------------
__global__ __launch_bounds__(256) void xt_kernel(
    const float* __restrict__ x, u16* __restrict__ xT)
{
  const int b = blockIdx.z, c0 = blockIdx.y * 64, n0 = blockIdx.x * 64;
  __shared__ __align__(16) float T[64][68];
  const int t = threadIdx.x;
  {
    const int cr = t >> 4, nc = (t & 15) * 4;
    #pragma unroll
    for (int ci = 0; ci < 4; ++ci) {
      const float4 v = *(const float4*)&x[((size_t)(b * CDIM + c0 + cr + ci * 16)) * NDIM + n0 + nc];
      *(float4*)&T[cr + ci * 16][nc] = v;
    }
  }
  __syncthreads();
  {
    const int n = t >> 2, g = t & 3;
    union { u16 u[16]; uint4 v[2]; } pk;
    #pragma unroll
    for (int u_ = 0; u_ < 16; ++u_) pk.u[u_] = f2bf(T[g * 16 + u_][n]);
    uint4* dst = (uint4*)&xT[((size_t)(b * NDIM + n0 + n)) * CDIM + c0 + g * 16];
    dst[0] = pk.v[0]; dst[1] = pk.v[1];
  }
}

// ---------------- fused Q/K/V projection, W direct-from-global bf16 ----------------
// Grid (NDIM/64, 6, BDIM): p = y>>1, o0 = (y&1)*128.
// Q/K -> bf16 [b][n][256] head-major (Q scaled log2e/8 incl bias);
// V -> bf16 [b][c][n].
__global__ __launch_bounds__(256, 4) void qkv_kernel(
    const u16* __restrict__ xT, const u16* __restrict__ wb,
    const float* __restrict__ bq, const float* __restrict__ bk,
    const float* __restrict__ bv,
    u16* __restrict__ qT, u16* __restrict__ kT, u16* __restrict__ vB)
{
  const int b = blockIdx.z;
  const int p = blockIdx.y >> 1;
  const int o0 = (blockIdx.y & 1) * 128;
  const int n0 = blockIdx.x * 64;
  const float* bsel = (p == 0) ? bq : (p == 1) ? bk : bv;
  const float wscale = (p == 0) ? QSCALE : 1.0f;

  __shared__ __align__(16) u16 XTs[64][40];
  const int t = threadIdx.x, lane = t & 63, w = t >> 6;
  const int qd = lane >> 4, lm = lane & 15;
  const int sr = t >> 2, sg = (t & 3) * 8;

  const u16* xsrc = xT + ((size_t)(b * NDIM + n0 + sr)) * CDIM + sg;
  // per-lane W fragment rows (o = o0+32w+16j+lm, k-chunk = qd*8)
  const u16* wrow0 = wb + (size_t)p * WSZ + (size_t)(o0 + 32 * w + lm) * CDIM + qd * 8;
  const u16* wrow1 = wrow0 + (size_t)16 * CDIM;

  f32x4 acc[4][2];
  #pragma unroll
  for (int nt = 0; nt < 4; ++nt)
    #pragma unroll
    for (int j = 0; j < 2; ++j) acc[nt][j] = (f32x4){0.f, 0.f, 0.f, 0.f};

  for (int cs = 0; cs < 8; ++cs) {
    // W fragments from global (L2-hot); issued before barriers so latency hides
    const bf16x8 wf0 = *(const bf16x8*)(wrow0 + cs * 32);
    const bf16x8 wf1 = *(const bf16x8*)(wrow1 + cs * 32);
    __syncthreads();
    *(uint4*)&XTs[sr][sg] = *(const uint4*)(xsrc + cs * 32);
    __syncthreads();
    bf16x8 xf[4];
    #pragma unroll
    for (int nt = 0; nt < 4; ++nt) xf[nt] = *(const bf16x8*)&XTs[16 * nt + lm][qd * 8];
    #pragma unroll
    for (int nt = 0; nt < 4; ++nt) {
      if (p < 2) {
        acc[nt][0] = __builtin_amdgcn_mfma_f32_16x16x32_bf16(xf[nt], wf0, acc[nt][0], 0, 0, 0);
        acc[nt][1] = __builtin_amdgcn_mfma_f32_16x16x32_bf16(xf[nt], wf1, acc[nt][1], 0, 0, 0);
      } else {
        acc[nt][0] = __builtin_amdgcn_mfma_f32_16x16x32_bf16(wf0, xf[nt], acc[nt][0], 0, 0, 0);
        acc[nt][1] = __builtin_amdgcn_mfma_f32_16x16x32_bf16(wf1, xf[nt], acc[nt][1], 0, 0, 0);
      }
    }
  }

  if (p < 2) {
    // D[m=n][col=o]: n = n0+16nt+4qd+r, o = o0+32w+16j+lm
    u16* out = (p == 0) ? qT : kT;
    #pragma unroll
    for (int j = 0; j < 2; ++j) {
      const int og = o0 + 32 * w + 16 * j + lm;
      const float bv2 = bsel[og] * wscale;
      #pragma unroll
      for (int nt = 0; nt < 4; ++nt)
        #pragma unroll
        for (int r = 0; r < 4; ++r) {
          const int n = n0 + 16 * nt + 4 * qd + r;
          out[((size_t)(b * NDIM + n)) * CDIM + og] = f2bf(acc[nt][j][r] + bv2);
        }
    }
  } else {
    // D[m=o][col=n]: o = o0+32w+16j+4qd+r, n = n0+16nt+lm
    #pragma unroll
    for (int j = 0; j < 2; ++j) {
      const float4 b4 = *(const float4*)&bsel[o0 + 32 * w + 16 * j + 4 * qd];
      const float bvr[4] = {b4.x, b4.y, b4.z, b4.w};
      #pragma unroll
      for (int nt = 0; nt < 4; ++nt)
        #pragma unroll
        for (int r = 0; r < 4; ++r) {
          const int og = o0 + 32 * w + 16 * j + 4 * qd + r;
          const int n = n0 + 16 * nt + lm;
          vB[((size_t)(b * CDIM + og)) * NDIM + n] = f2bf(acc[nt][j][r] + bvr[r]);
        }
    }
  }
}

// ---------------- K-split(2) S^T-form MFMA flash attention (R14 body) ----------------
// global_load_lds staging, double-buffered 32KB LDS, 1 barrier/tile,
// XOR-16B-granule swizzle (source+read) for unpadded rows.
__global__ __launch_bounds__(256, 4) void attn_kernel(
    const u16* __restrict__ qT, const u16* __restrict__ kT,
    const u16* __restrict__ vB, u16* __restrict__ Opart,
    float* __restrict__ Lp)
{
  const int bh = blockIdx.y, b = bh >> 2, h = bh & 3;
  const int n0 = blockIdx.x * 128;
  const int z  = blockIdx.z;

  // [buf][0]=K tile, [buf][1]=V tile. 2*2*64*64*2B = 32768 B.
  __shared__ __align__(16) u16 KVlds[2][2][64][64];

  const int t = threadIdx.x, lane = t & 63, w = t >> 6;
  const int qd = lane >> 4, lm = lane & 15, l7 = lm & 7;

  // Q fragments straight from global: rows are wave-private, read once.
  bf16x8 qf[2][2];
  {
    const u16* qbase = qT + ((size_t)(b * NDIM) + n0) * CDIM + h * 64;
    #pragma unroll
    for (int s = 0; s < 2; ++s)
      #pragma unroll
      for (int hh = 0; hh < 2; ++hh)
        qf[s][hh] = *(const bf16x8*)(qbase +
            (size_t)(16 * (2 * w + s) + lm) * CDIM + 32 * hh + qd * 8);
  }

  float l_i[2] = {0.f, 0.f};
  f32x4 oa[2][4];
  #pragma unroll
  for (int s = 0; s < 2; ++s)
    #pragma unroll
    for (int dt = 0; dt < 4; ++dt) oa[s][dt] = (f32x4){0.f, 0.f, 0.f, 0.f};

  // staging: wave w, issue i covers LDS rows 8*(4i+w)..+8; lane -> row 8*(4i+w)+(lane>>3),
  // 16B granule (lane&7), source granule pre-swizzled: ^(row&7) = ^(lane>>3).
  const int srow = lane >> 3;
  const int swz  = 8 * ((lane & 7) ^ srow);       // elems
  const u16* kp0 = kT + ((size_t)(b * NDIM + z * KPERZ + 8 * w + srow)) * CDIM + h * 64 + swz;
  const u16* kp1 = kp0 + (size_t)32 * CDIM;
  const u16* vp0 = vB + ((size_t)(b * CDIM + h * 64 + 8 * w + srow)) * NDIM + z * KPERZ + swz;
  const u16* vp1 = vp0 + (size_t)32 * NDIM;

  // prologue: stage tile 0 into buf 0
  {
    u16* kb = &KVlds[0][0][0][0];
    u16* vb2 = &KVlds[0][1][0][0];
    gload16(kp0, kb + w * 512);
    gload16(kp1, kb + (4 + w) * 512);
    gload16(vp0, vb2 + w * 512);
    gload16(vp1, vb2 + (4 + w) * 512);
  }

  #pragma unroll 1
  for (int it = 0; it < KPERZ / 64; ++it) {
    __syncthreads();   // vmcnt(0) drain: tile 'it' landed; all waves synced
    if (it + 1 < KPERZ / 64) {
      // issue next tile into the other buffer; lands by next barrier
      const size_t ko = (size_t)(it + 1) * 64 * CDIM;
      const int    vo = (it + 1) * 64;
      u16* kb = &KVlds[(it + 1) & 1][0][0][0];
      u16* vb2 = &KVlds[(it + 1) & 1][1][0][0];
      gload16(kp0 + ko, kb + w * 512);
      gload16(kp1 + ko, kb + (4 + w) * 512);
      gload16(vp0 + vo, vb2 + w * 512);
      gload16(vp1 + vo, vb2 + (4 + w) * 512);
    }
    const u16 (*Kt)[64] = KVlds[it & 1][0];
    const u16 (*Vt)[64] = KVlds[it & 1][1];

    // P fragments, packed bf16 at production: pk[s][c].v is the PV B-operand
    union { u16 u[4]; s16x4 v; } pk[2][4];
    float rs[2] = {0.f, 0.f};

    #pragma unroll
    for (int nt = 0; nt < 4; ++nt) {
      // swizzled read: granule (4hh+qd) ^ (row&7), row&7 == lm&7
      const bf16x8 kf0 = *(const bf16x8*)&Kt[16 * nt + lm][8 * (qd ^ l7)];
      const bf16x8 kf1 = *(const bf16x8*)&Kt[16 * nt + lm][8 * ((4 + qd) ^ l7)];
      #pragma unroll
      for (int s = 0; s < 2; ++s) {
        f32x4 zz = (f32x4){0.f, 0.f, 0.f, 0.f};
        zz = __builtin_amdgcn_mfma_f32_16x16x32_bf16(kf0, qf[s][0], zz, 0, 0, 0);
        zz = __builtin_amdgcn_mfma_f32_16x16x32_bf16(kf1, qf[s][1], zz, 0, 0, 0);
        #pragma unroll
        for (int r = 0; r < 4; ++r) {
          const float p = __builtin_amdgcn_exp2f(zz[r]);
          pk[s][nt].u[r] = f2bf(p);
          rs[s] += p;
        }
      }
    }
    l_i[0] += rs[0];
    l_i[1] += rs[1];

    #pragma unroll
    for (int c = 0; c < 4; ++c) {
      s16x4 av[4];
      #pragma unroll
      for (int dt = 0; dt < 4; ++dt)
        av[dt] = *(const s16x4*)&Vt[16 * dt + lm][(16 * c + 4 * qd) ^ (8 * l7)];
      #pragma unroll
      for (int dt = 0; dt < 4; ++dt) {
        oa[0][dt] = __builtin_amdgcn_mfma_f32_16x16x16bf16_1k(av[dt], pk[0][c].v, oa[0][dt], 0, 0, 0);
        oa[1][dt] = __builtin_amdgcn_mfma_f32_16x16x16bf16_1k(av[dt], pk[1][c].v, oa[1][dt], 0, 0, 0);
      }
    }
  }

  // deferred l reduction across the 4 quads (lane bits 4,5)
  #pragma unroll
  for (int s = 0; s < 2; ++s) {
    l_i[s] += __shfl_xor(l_i[s], 16);
    l_i[s] += __shfl_xor(l_i[s], 32);
  }

  __syncthreads();   // all waves done reading the last tile before overlay
  // epilogue: normalize, transpose via LDS (overlay KV region), write rows.
  u16 (*Ot)[72] = (u16(*)[72])&KVlds[0][0][0][0];   // [128][72] = 18432B fits
  #pragma unroll
  for (int s = 0; s < 2; ++s) {
    const float inv = 1.0f / l_i[s];
    #pragma unroll
    for (int dt = 0; dt < 4; ++dt)
      #pragma unroll
      for (int r = 0; r < 4; ++r)
        Ot[16 * (2 * w + s) + lm][16 * dt + 4 * qd + r] = f2bf(oa[s][dt][r] * inv);
  }
  if (qd == 0) {
    const size_t lbase = ((size_t)z * (BDIM * HDIM) + bh) * NDIM;
    #pragma unroll
    for (int s = 0; s < 2; ++s)
      Lp[lbase + n0 + 16 * (2 * w + s) + lm] = l_i[s];
  }
  __syncthreads();
  {
    const int r = t >> 1, g = (t & 1) * 32;
    u16* dst = Opart + (((size_t)z * (BDIM * HDIM) + bh) * NDIM + n0 + r) * DKDIM + g;
    const uint4* srcp = (const uint4*)&Ot[r][g];
    uint4* d4 = (uint4*)dst;
    d4[0] = srcp[0]; d4[1] = srcp[1]; d4[2] = srcp[2]; d4[3] = srcp[3];
  }
}

// ---------------- output projection, W direct-from-global bf16, 2-way combine ----------------
// Grid (NDIM/64, 2, BDIM). Combine weights = l ratios (shift-free partials).
__global__ __launch_bounds__(256, 4) void projout_kernel(
    const u16* __restrict__ Opart, const float* __restrict__ Lp,
    const u16* __restrict__ wb, const float* __restrict__ bp,
    const float* __restrict__ res, float* __restrict__ out)
{
  const int b = blockIdx.z, o0 = blockIdx.y * 128, n0 = blockIdx.x * 64;
  __shared__ __align__(16) u16 XTs[64][40];
  const int t = threadIdx.x, lane = t & 63, w = t >> 6;
  const int qd = lane >> 4, lm = lane & 15;
  const int sr = t >> 2, sg = (t & 3) * 8;

  float wh[4][NSPLIT];
  #pragma unroll
  for (int hh = 0; hh < 4; ++hh) {
    const size_t i0 = ((size_t)(b * HDIM + hh)) * NDIM + n0 + sr;
    float l[NSPLIT], tot = 0.f;
    #pragma unroll
    for (int zz = 0; zz < NSPLIT; ++zz) { l[zz] = Lp[(size_t)zz * NQ + i0]; tot += l[zz]; }
    const float iv = 1.0f / tot;
    #pragma unroll
    for (int zz = 0; zz < NSPLIT; ++zz) wh[hh][zz] = l[zz] * iv;
  }

  // per-lane W fragment rows from pre-converted bf16 wp
  const u16* wrow0 = wb + (size_t)3 * WSZ + (size_t)(o0 + 32 * w + lm) * CDIM + qd * 8;
  const u16* wrow1 = wrow0 + (size_t)16 * CDIM;

  f32x4 acc[4][2];
  #pragma unroll
  for (int nt = 0; nt < 4; ++nt)
    #pragma unroll
    for (int j = 0; j < 2; ++j) acc[nt][j] = (f32x4){0.f, 0.f, 0.f, 0.f};

  for (int cs = 0; cs < 8; ++cs) {
    const int c0 = cs * 32;
    const int hh = c0 >> 6;
    const int dk = (c0 & 63) + sg;
    const bf16x8 wf0 = *(const bf16x8*)(wrow0 + c0);
    const bf16x8 wf1 = *(const bf16x8*)(wrow1 + c0);
    __syncthreads();
    {
      const size_t obase = (((size_t)(b * HDIM + hh)) * NDIM + n0 + sr) * DKDIM + dk;
      float v[8] = {0.f, 0.f, 0.f, 0.f, 0.f, 0.f, 0.f, 0.f};
      #pragma unroll
      for (int zz = 0; zz < NSPLIT; ++zz) {
        union { u16 u[8]; uint4 q; } a;
        a.q = *(const uint4*)(Opart + (size_t)zz * NQ * DKDIM + obase);
        const float wz = wh[hh][zz];
        #pragma unroll
        for (int j = 0; j < 8; ++j) v[j] = fmaf(wz, bf2f(a.u[j]), v[j]);
      }
      union { u16 u[8]; uint4 q; } ov;
      #pragma unroll
      for (int j = 0; j < 8; ++j) ov.u[j] = f2bf(v[j]);
      *(uint4*)&XTs[sr][sg] = ov.q;
    }
    __syncthreads();
    bf16x8 xf[4];
    #pragma unroll
    for (int nt = 0; nt < 4; ++nt) xf[nt] = *(const bf16x8*)&XTs[16 * nt + lm][qd * 8];
    #pragma unroll
    for (int nt = 0; nt < 4; ++nt) {
      acc[nt][0] = __builtin_amdgcn_mfma_f32_16x16x32_bf16(wf0, xf[nt], acc[nt][0], 0, 0, 0);
      acc[nt][1] = __builtin_amdgcn_mfma_f32_16x16x32_bf16(wf1, xf[nt], acc[nt][1], 0, 0, 0);
    }
  }

  // D[m=o][col=n]: o = o0+32w+16j+4qd+r, n = n0+16nt+lm
  #pragma unroll
  for (int j = 0; j < 2; ++j) {
    const float4 b4 = *(const float4*)&bp[o0 + 32 * w + 16 * j + 4 * qd];
    const float bvr[4] = {b4.x, b4.y, b4.z, b4.w};
    #pragma unroll
    for (int nt = 0; nt < 4; ++nt)
      #pragma unroll
      for (int r = 0; r < 4; ++r) {
        const int og = o0 + 32 * w + 16 * j + 4 * qd + r;
        const int n = n0 + 16 * nt + lm;
        const size_t idx = ((size_t)(b * CDIM + og)) * NDIM + n;
        out[idx] = acc[nt][j][r] + bvr[r] + res[idx];
      }
  }
}

extern "C" void kernel_launch(void* const* d_in, const int* in_sizes, int n_in,
                              void* d_out, int out_size, void* d_ws, size_t ws_size,
                              hipStream_t stream)
{
  const float* x  = (const float*)d_in[0];
  const float* wq = (const float*)d_in[1];
  const float* bq = (const float*)d_in[2];
  const float* wk = (const float*)d_in[3];
  const float* bk = (const float*)d_in[4];
  const float* wv = (const float*)d_in[5];
  const float* bv = (const float*)d_in[6];
  const float* wp = (const float*)d_in[7];
  const float* bp = (const float*)d_in[8];
  float* out = (float*)d_out;

  const size_t sz = (size_t)BDIM * CDIM * NDIM;   // 4.19M elements
  u16* xTb = (u16*)d_ws;
  u16* qTb = xTb + sz;
  u16* kTb = qTb + sz;
  u16* vBb = kTb + sz;
  u16* Opart = vBb + sz;                          // NSPLIT*sz u16
  float* Lp = (float*)(Opart + (size_t)NSPLIT * sz);  // NSPLIT*NQ floats
  u16* wbf = (u16*)(Lp + (size_t)NSPLIT * NQ);    // 4*WSZ u16 (512KB)

  const dim3 blk(256);
  wconv_kernel<<<dim3(WSZ / (256 * 8), 4, 1), blk, 0, stream>>>(wq, wk, wv, wp, wbf);
  xt_kernel<<<dim3(NDIM / 64, CDIM / 64, BDIM), blk, 0, stream>>>(x, xTb);
  qkv_kernel<<<dim3(NDIM / 64, 6, BDIM), blk, 0, stream>>>(
      xTb, wbf, bq, bk, bv, qTb, kTb, vBb);
  attn_kernel<<<dim3(NDIM / 128, BDIM * HDIM, NSPLIT), blk, 0, stream>>>(
      qTb, kTb, vBb, Opart, Lp);
  projout_kernel<<<dim3(NDIM / 64, 2, BDIM), blk, 0, stream>>>(
      Opart, Lp, wbf, bp, x, out);
}